// Round 1
// baseline (1997.477 us; speedup 1.0000x reference)
//
#include <hip/hip_runtime.h>

#define HW 4096

// ---------------------------------------------------------------------------
// pack [map, start, goal] -> [16][3][64][64]
// ---------------------------------------------------------------------------
__global__ __launch_bounds__(256) void pack3_kernel(
    const float* __restrict__ m, const float* __restrict__ s,
    const float* __restrict__ g, float* __restrict__ in3)
{
  int idx = blockIdx.x * 256 + threadIdx.x;
  if (idx >= 16 * 3 * HW) return;
  int p = idx & (HW - 1);
  int bc = idx >> 12;
  int c = bc % 3, b = bc / 3;
  const float* src = (c == 0) ? m : ((c == 1) ? s : g);
  in3[idx] = src[b * HW + p];
}

// ---------------------------------------------------------------------------
// weight transpose: w[co][c][3][3] -> wt[(c*9+tap)][co]   (coalesced staging)
// ---------------------------------------------------------------------------
__global__ __launch_bounds__(256) void wtrans_kernel(
    const float* __restrict__ w, float* __restrict__ wt, int cin, int cout)
{
  int idx = blockIdx.x * 256 + threadIdx.x;
  int total = cin * 9 * cout;
  if (idx >= total) return;
  int co = idx % cout;
  int rest = idx / cout;              // c*9+tap
  wt[idx] = w[co * cin * 9 + rest];
}

// ---------------------------------------------------------------------------
// direct 3x3 conv + bias + BN(eval) + optional ReLU.  16x16 spatial tile,
// CT<=64 output channels per block; thread = 4 pixels x 16 couts.
// ---------------------------------------------------------------------------
template<int CIN, int COUT, int CK, bool RELU>
__global__ __launch_bounds__(256) void conv3x3_kernel(
    const float* __restrict__ in,    // [nb][CIN][64][64]
    float* __restrict__ out,         // [nb][COUT][64][64]
    const float* __restrict__ wt,    // [(c*9+tap)][COUT]
    const float* __restrict__ bconv,
    const float* __restrict__ gamma, const float* __restrict__ beta)
{
  constexpr int CT  = (COUT < 64) ? COUT : 64;
  constexpr int NCG = CT / 16;
  constexpr int NT  = 64 * NCG;
  __shared__ float sIn[CK][18][18];
  __shared__ float sW[CK][9][CT];
  const int tile = blockIdx.x;
  const int cog0 = blockIdx.y * CT;
  const int b    = blockIdx.z;
  const int y0 = (tile >> 2) << 4, x0 = (tile & 3) << 4;
  const int tid = threadIdx.x;
  const int cg = tid >> 6;
  const int pg = tid & 63;
  const int py = pg >> 2, px0 = (pg & 3) << 2;

  float acc[4][16];
  #pragma unroll
  for (int i = 0; i < 4; ++i)
    #pragma unroll
    for (int j = 0; j < 16; ++j) acc[i][j] = 0.f;

  for (int cc = 0; cc < CIN; cc += CK) {
    __syncthreads();
    for (int idx = tid; idx < CK * 324; idx += NT) {
      int c = idx / 324, rem = idx - c * 324;
      int iy = rem / 18, ix = rem - iy * 18;
      int gy = y0 - 1 + iy, gx = x0 - 1 + ix;
      float v = 0.f;
      if ((unsigned)gy < 64u && (unsigned)gx < 64u)
        v = in[(((size_t)b * CIN + cc + c) << 12) + (gy << 6) + gx];
      sIn[c][iy][ix] = v;
    }
    for (int idx = tid; idx < CK * 9 * CT; idx += NT) {
      int co = idx % CT;
      int rest = idx / CT;
      int tap = rest % 9, c = rest / 9;
      sW[c][tap][co] = wt[((size_t)(cc + c) * 9 + tap) * COUT + cog0 + co];
    }
    __syncthreads();
    #pragma unroll
    for (int c = 0; c < CK; ++c) {
      #pragma unroll
      for (int dy = 0; dy < 3; ++dy) {
        float r[6];
        #pragma unroll
        for (int j = 0; j < 6; ++j) r[j] = sIn[c][py + dy][px0 + j];
        #pragma unroll
        for (int dx = 0; dx < 3; ++dx) {
          float wv[16];
          #pragma unroll
          for (int j = 0; j < 16; ++j) wv[j] = sW[c][dy * 3 + dx][cg * 16 + j];
          #pragma unroll
          for (int i = 0; i < 4; ++i)
            #pragma unroll
            for (int j = 0; j < 16; ++j)
              acc[i][j] = fmaf(r[dx + i], wv[j], acc[i][j]);
        }
      }
    }
  }
  #pragma unroll
  for (int j = 0; j < 16; ++j) {
    int co = cog0 + cg * 16 + j;
    float sc = gamma[co] / sqrtf(1.0f + 1e-5f);
    float bb = bconv[co], sh = beta[co];
    #pragma unroll
    for (int i = 0; i < 4; ++i) {
      float v = (acc[i][j] + bb) * sc + sh;
      if (RELU) v = fmaxf(v, 0.f);
      out[(((size_t)b * COUT + co) << 12) + ((y0 + py) << 6) + (x0 + px0 + i)] = v;
    }
  }
}

// ---------------------------------------------------------------------------
// last conv (256->1) + BN (no relu) + the three 1x1 heads fused.
// ---------------------------------------------------------------------------
__global__ __launch_bounds__(256) void conv_l4_heads_kernel(
    const float* __restrict__ in,       // [nb][256][64][64]
    const float* __restrict__ w4,       // [256*9]
    const float* __restrict__ b4, const float* __restrict__ gm4,
    const float* __restrict__ bt4,
    const float* __restrict__ cw, const float* __restrict__ cb,
    const float* __restrict__ gw, const float* __restrict__ gb,
    const float* __restrict__ ow, const float* __restrict__ ob,
    float* __restrict__ costout,        // [16][4096]  (global batch index)
    float* __restrict__ geoout, float* __restrict__ obsout,  // d_out regions
    int b0)
{
  __shared__ float sIn[8][18][18];
  __shared__ float sW[8][9];
  const int tile = blockIdx.x, b = blockIdx.y;
  const int y0 = (tile >> 2) << 4, x0 = (tile & 3) << 4;
  const int tid = threadIdx.x;
  const int py = tid >> 4, px = tid & 15;
  float acc = 0.f;
  for (int cc = 0; cc < 256; cc += 8) {
    __syncthreads();
    for (int idx = tid; idx < 8 * 324; idx += 256) {
      int c = idx / 324, rem = idx - c * 324;
      int iy = rem / 18, ix = rem - iy * 18;
      int gy = y0 - 1 + iy, gx = x0 - 1 + ix;
      float v = 0.f;
      if ((unsigned)gy < 64u && (unsigned)gx < 64u)
        v = in[(((size_t)b * 256 + cc + c) << 12) + (gy << 6) + gx];
      sIn[c][iy][ix] = v;
    }
    if (tid < 72) sW[tid / 9][tid % 9] = w4[(cc + tid / 9) * 9 + tid % 9];
    __syncthreads();
    #pragma unroll
    for (int c = 0; c < 8; ++c)
      #pragma unroll
      for (int dy = 0; dy < 3; ++dy)
        #pragma unroll
        for (int dx = 0; dx < 3; ++dx)
          acc = fmaf(sIn[c][py + dy][px + dx], sW[c][dy * 3 + dx], acc);
  }
  float sc = gm4[0] / sqrtf(1.0f + 1e-5f);
  float f  = (acc + b4[0]) * sc + bt4[0];
  float cv = 1.f / (1.f + expf(-(f * cw[0] + cb[0])));
  float gv = fmaxf(f * gw[0] + gb[0], 0.f);
  float ov = fmaxf(f * ow[0] + ob[0], 0.f);
  int gbi = b0 + b;
  int pix = ((y0 + py) << 6) + (x0 + px);
  costout[gbi * HW + pix] = cv;
  geoout[gbi * HW + pix]  = gv;
  obsout[gbi * HW + pix]  = ov;
}

// ---------------------------------------------------------------------------
// A* pass 1: one block (= one wave) per batch, free-running 512 steps.
// State in LDS; per-row (max, first-idx) kept in per-lane registers;
// journal (ind, solved bit, parent-updated cells) written to global.
// Obstacles are encoded as hist=1 (never expandable) -- output hist comes
// from the journal, not from this internal array.
// ---------------------------------------------------------------------------
__global__ __launch_bounds__(64) void astar_pass1_kernel(
    const float* __restrict__ costm,
    const float* __restrict__ startm,
    const float* __restrict__ goalm,
    const float* __restrict__ mapd,
    unsigned short* __restrict__ Jmeta,   // [16][512]  ind | solved<<15
    unsigned short* __restrict__ Jcells)  // [16][512][8]
{
  __shared__ float fe[HW];
  __shared__ float g[HW];
  __shared__ float hs[HW];
  __shared__ unsigned char open_[HW];
  __shared__ unsigned char hist_[HW];
  const int b = blockIdx.x, lane = threadIdx.x;

  // goal index
  int gi = 0x7fffffff;
  for (int i = lane; i < HW; i += 64)
    if (goalm[b * HW + i] > 0.5f) gi = min(gi, i);
  #pragma unroll
  for (int m = 32; m; m >>= 1) gi = min(gi, __shfl_xor(gi, m));
  const int goal_idx = gi;
  const float gyf = (float)(goal_idx >> 6), gxf = (float)(goal_idx & 63);

  for (int i = lane; i < HW; i += 64) {
    float c_ = costm[b * HW + i];
    float iy = (float)(i >> 6), ix = (float)(i & 63);
    float d0 = fabsf(iy - gyf), d1 = fabsf(ix - gxf);
    float cheb = (d0 + d1) - fminf(d0, d1);
    float euc  = sqrtf(d0 * d0 + d1 * d1);
    float h = (cheb + 0.001f * euc) + c_;     // heuristic + cost (matches ref order)
    hs[i] = h;
    g[i]  = 0.f;
    bool st = startm[b * HW + i] > 0.5f;
    open_[i] = st ? 1 : 0;
    hist_[i] = (mapd[b * HW + i] > 0.5f) ? 0 : 1;   // obstacle -> blocked forever
    // f = 0.5*g + 0.5*h with g=0  ->  0.5*h ; exp(-f/8), /8 exact as *0.125
    fe[i] = st ? expf(-((0.5f * h) * 0.125f)) : 0.f;
  }
  __syncthreads();

  // per-lane row registers: (max, first index achieving max) of row `lane`
  float gm = -1.f; int gidx = 0;
  {
    int base = lane << 6;
    for (int k = 0; k < 64; ++k) {
      int ci = base + ((k + lane) & 63);        // rotated to avoid bank conflicts
      float v = fe[ci];
      if (v > gm || (v == gm && ci < gidx)) { gm = v; gidx = ci; }
    }
  }

  for (int t = 0; t < 512; ++t) {
    // ---- global argmax (first-index tie-break, matches jnp.argmax) ----
    float v = gm; int idx = gidx;
    #pragma unroll
    for (int m = 32; m; m >>= 1) {
      float vo = __shfl_xor(v, m);
      int   io = __shfl_xor(idx, m);
      if (vo > v || (vo == v && io < idx)) { v = vo; idx = io; }
    }
    const int ind = idx;
    const bool unsolved = (ind != goal_idx);
    const int r = ind >> 6;
    const float g2 = g[ind] + costm[b * HW + ind];

    int pcell = -1; float pval = 0.f;
    if (lane < 8) {
      int kk = (lane >= 4) ? lane + 1 : lane;        // skip center tap
      int ny = r + (kk / 3 - 1), nx = (ind & 63) + (kk % 3 - 1);
      if ((unsigned)ny < 64u && (unsigned)nx < 64u) {
        int n = (ny << 6) + nx;
        bool trig;
        if (open_[n]) trig = (g[n] > g2);
        else          trig = (hist_[n] == 0);
        if (trig) {
          g[n] = g2;
          open_[n] = 1;
          float fv = expf(-((0.5f * g2 + 0.5f * hs[n]) * 0.125f));
          fe[n] = fv;
          pcell = n; pval = fv;
        }
      }
      Jcells[((size_t)b * 512 + t) * 8 + lane] =
          (unsigned short)(pcell >= 0 ? pcell : 0xFFFF);
    } else if (lane == 8) {
      hist_[ind] = 1;
      if (unsolved) { open_[ind] = 0; fe[ind] = 0.f; }
      Jmeta[b * 512 + t] = (unsigned short)(ind | (unsolved ? 0 : 0x8000));
    }
    __syncthreads();

    // ---- rescan selected row (covers the only possible decrease) ----
    {
      int ci = (r << 6) + lane;
      float bv = fe[ci]; int bi2 = ci;
      #pragma unroll
      for (int m = 32; m; m >>= 1) {
        float vo = __shfl_xor(bv, m);
        int   io = __shfl_xor(bi2, m);
        if (vo > bv || (vo == bv && io < bi2)) { bv = vo; bi2 = io; }
      }
      if (lane == r) { gm = bv; gidx = bi2; }
    }
    // ---- monotone-increase patches for the other rows ----
    #pragma unroll
    for (int k = 0; k < 8; ++k) {
      int   pc = __shfl(pcell, k);
      float pv = __shfl(pval, k);
      if (pc >= 0 && lane != r && (pc >> 6) == lane) {
        if (pv > gm || (pv == gm && pc < gidx)) { gm = pv; gidx = pc; }
      }
    }
    __syncthreads();
  }
}

// ---------------------------------------------------------------------------
// A* pass 2: t* = first t where all 16 batches selected their goal; replay
// journal for t<=t*, then backtrack.  One block (one wave) per batch.
// ---------------------------------------------------------------------------
__global__ __launch_bounds__(64) void astar_pass2_kernel(
    const unsigned short* __restrict__ Jmeta,
    const unsigned short* __restrict__ Jcells,
    const float* __restrict__ goalm,
    float* __restrict__ out_hist, float* __restrict__ out_path)
{
  __shared__ unsigned short par[HW];
  __shared__ unsigned short jm[64];
  __shared__ unsigned short jc[64][8];
  const int b = blockIdx.x, lane = threadIdx.x;

  for (int i = lane; i < HW; i += 64) {
    out_hist[b * HW + i] = 0.f;
    out_path[b * HW + i] = 0.f;
  }
  // t_last
  int localmin = 512;
  for (int t = lane; t < 512; t += 64) {
    bool all16 = true;
    for (int bb = 0; bb < 16; ++bb)
      all16 = all16 && ((Jmeta[bb * 512 + t] & 0x8000u) != 0);
    if (all16) localmin = min(localmin, t);
  }
  #pragma unroll
  for (int m = 32; m; m >>= 1) localmin = min(localmin, __shfl_xor(localmin, m));
  const int t_last = (localmin < 512) ? localmin : 511;

  // goal index
  int gi = 0x7fffffff;
  for (int i = lane; i < HW; i += 64)
    if (goalm[b * HW + i] > 0.5f) gi = min(gi, i);
  #pragma unroll
  for (int m = 32; m; m >>= 1) gi = min(gi, __shfl_xor(gi, m));

  for (int i = lane; i < HW; i += 64) par[i] = (unsigned short)gi;
  __syncthreads();

  // replay journal t = 0..t_last (inclusive)
  for (int t0 = 0; t0 <= t_last; t0 += 64) {
    if (t0 + lane < 512) {
      jm[lane] = Jmeta[b * 512 + t0 + lane];
      const unsigned short* src = &Jcells[((size_t)b * 512 + t0 + lane) * 8];
      #pragma unroll
      for (int k = 0; k < 8; ++k) jc[lane][k] = src[k];
    }
    __syncthreads();
    int te = min(t_last - t0, 63);
    for (int tt = 0; tt <= te; ++tt) {
      int ind = jm[tt] & 0x0FFF;
      if (lane < 8) {
        unsigned short c = jc[tt][lane];
        if (c != 0xFFFFu) par[c] = (unsigned short)ind;
      } else if (lane == 8) {
        out_hist[b * HW + ind] = 1.0f;
      }
    }
    __syncthreads();
  }
  // backtrack
  if (lane == 0) {
    out_path[b * HW + gi] = 1.0f;
    int loc = par[gi];
    for (int i = 0; i < t_last; ++i) {
      out_path[b * HW + loc] = 1.0f;
      loc = par[loc];
    }
  }
}

// ---------------------------------------------------------------------------
extern "C" void kernel_launch(void* const* d_in, const int* in_sizes, int n_in,
                              void* d_out, int out_size, void* d_ws, size_t ws_size,
                              hipStream_t stream)
{
  (void)in_sizes; (void)n_in; (void)out_size;
  const float* mapd   = (const float*)d_in[0];
  const float* startm = (const float*)d_in[1];
  const float* goalm  = (const float*)d_in[2];
  const float* w0 = (const float*)d_in[3];
  const float* b0 = (const float*)d_in[4];
  const float* gm0= (const float*)d_in[5];
  const float* bt0= (const float*)d_in[6];
  const float* w1 = (const float*)d_in[7];
  const float* b1 = (const float*)d_in[8];
  const float* gm1= (const float*)d_in[9];
  const float* bt1= (const float*)d_in[10];
  const float* w2 = (const float*)d_in[11];
  const float* b2 = (const float*)d_in[12];
  const float* gm2= (const float*)d_in[13];
  const float* bt2= (const float*)d_in[14];
  const float* w3 = (const float*)d_in[15];
  const float* b3 = (const float*)d_in[16];
  const float* gm3= (const float*)d_in[17];
  const float* bt3= (const float*)d_in[18];
  const float* w4 = (const float*)d_in[19];
  const float* b4 = (const float*)d_in[20];
  const float* gm4= (const float*)d_in[21];
  const float* bt4= (const float*)d_in[22];
  const float* cw = (const float*)d_in[23];
  const float* cb = (const float*)d_in[24];
  const float* gw = (const float*)d_in[25];
  const float* gb = (const float*)d_in[26];
  const float* owp= (const float*)d_in[27];
  const float* obp= (const float*)d_in[28];
  float* out = (float*)d_out;

  float* wsf = (float*)d_ws;
  size_t off = 0;
  auto alloc = [&](size_t n) { float* p = wsf + off; off += n; return p; };
  float* wt0 = alloc(3 * 9 * 32);
  float* wt1 = alloc(32 * 9 * 64);
  float* wt2 = alloc(64 * 9 * 128);
  float* wt3 = alloc(128 * 9 * 256);
  float* in3   = alloc(16 * 3 * HW);
  float* costb = alloc(16 * HW);
  unsigned short* Jmeta  = (unsigned short*)alloc(16 * 512 / 2);
  unsigned short* Jcells = (unsigned short*)alloc(16 * 512 * 8 / 2);
  size_t fixed = off;

  // conv batch-group size: largest G whose ping-pong buffers fit the workspace
  int G = 16;
  while (G > 1 && (fixed + (size_t)G * 1572864ull) * sizeof(float) > ws_size) G >>= 1;
  float* bufA = alloc((size_t)G * 524288);    // up to 128 ch per batch
  float* bufB = alloc((size_t)G * 1048576);   // up to 256 ch per batch

  pack3_kernel<<<(16 * 3 * HW + 255) / 256, 256, 0, stream>>>(mapd, startm, goalm, in3);
  wtrans_kernel<<<(3 * 9 * 32 + 255) / 256, 256, 0, stream>>>(w0, wt0, 3, 32);
  wtrans_kernel<<<(32 * 9 * 64 + 255) / 256, 256, 0, stream>>>(w1, wt1, 32, 64);
  wtrans_kernel<<<(64 * 9 * 128 + 255) / 256, 256, 0, stream>>>(w2, wt2, 64, 128);
  wtrans_kernel<<<(128 * 9 * 256 + 255) / 256, 256, 0, stream>>>(w3, wt3, 128, 256);

  for (int g0 = 0; g0 < 16; g0 += G) {
    conv3x3_kernel<3, 32, 3, true><<<dim3(16, 1, G), 128, 0, stream>>>(
        in3 + (size_t)g0 * 3 * HW, bufA, wt0, b0, gm0, bt0);
    conv3x3_kernel<32, 64, 8, true><<<dim3(16, 1, G), 256, 0, stream>>>(
        bufA, bufB, wt1, b1, gm1, bt1);
    conv3x3_kernel<64, 128, 8, true><<<dim3(16, 2, G), 256, 0, stream>>>(
        bufB, bufA, wt2, b2, gm2, bt2);
    conv3x3_kernel<128, 256, 8, true><<<dim3(16, 4, G), 256, 0, stream>>>(
        bufA, bufB, wt3, b3, gm3, bt3);
    conv_l4_heads_kernel<<<dim3(16, G), 256, 0, stream>>>(
        bufB, w4, b4, gm4, bt4, cw, cb, gw, gb, owp, obp,
        costb, out + 2 * 16 * HW, out + 3 * 16 * HW, g0);
  }

  astar_pass1_kernel<<<16, 64, 0, stream>>>(costb, startm, goalm, mapd, Jmeta, Jcells);
  astar_pass2_kernel<<<16, 64, 0, stream>>>(Jmeta, Jcells, goalm, out, out + 16 * HW);
}

// Round 2
// 1172.784 us; speedup vs baseline: 1.7032x; 1.7032x over previous
//
#include <hip/hip_runtime.h>

#define HW 4096

// ---------------------------------------------------------------------------
// pack [map, start, goal] -> [16][3][64][64]
// ---------------------------------------------------------------------------
__global__ __launch_bounds__(256) void pack3_kernel(
    const float* __restrict__ m, const float* __restrict__ s,
    const float* __restrict__ g, float* __restrict__ in3)
{
  int idx = blockIdx.x * 256 + threadIdx.x;
  if (idx >= 16 * 3 * HW) return;
  int p = idx & (HW - 1);
  int bc = idx >> 12;
  int c = bc % 3, b = bc / 3;
  const float* src = (c == 0) ? m : ((c == 1) ? s : g);
  in3[idx] = src[b * HW + p];
}

// ---------------------------------------------------------------------------
// weight transpose: w[co][c][3][3] -> wt[(c*9+tap)][co]   (coalesced staging)
// ---------------------------------------------------------------------------
__global__ __launch_bounds__(256) void wtrans_kernel(
    const float* __restrict__ w, float* __restrict__ wt, int cin, int cout)
{
  int idx = blockIdx.x * 256 + threadIdx.x;
  int total = cin * 9 * cout;
  if (idx >= total) return;
  int co = idx % cout;
  int rest = idx / cout;              // c*9+tap
  wt[idx] = w[co * cin * 9 + rest];
}

// ---------------------------------------------------------------------------
// direct 3x3 conv + bias + BN(eval) + optional ReLU.  16x16 spatial tile,
// CT<=64 output channels per block; thread = 4 pixels x 16 couts.
// ---------------------------------------------------------------------------
template<int CIN, int COUT, int CK, bool RELU>
__global__ __launch_bounds__(256) void conv3x3_kernel(
    const float* __restrict__ in,    // [nb][CIN][64][64]
    float* __restrict__ out,         // [nb][COUT][64][64]
    const float* __restrict__ wt,    // [(c*9+tap)][COUT]
    const float* __restrict__ bconv,
    const float* __restrict__ gamma, const float* __restrict__ beta)
{
  constexpr int CT  = (COUT < 64) ? COUT : 64;
  constexpr int NCG = CT / 16;
  constexpr int NT  = 64 * NCG;
  __shared__ float sIn[CK][18][18];
  __shared__ float sW[CK][9][CT];
  const int tile = blockIdx.x;
  const int cog0 = blockIdx.y * CT;
  const int b    = blockIdx.z;
  const int y0 = (tile >> 2) << 4, x0 = (tile & 3) << 4;
  const int tid = threadIdx.x;
  const int cg = tid >> 6;
  const int pg = tid & 63;
  const int py = pg >> 2, px0 = (pg & 3) << 2;

  float acc[4][16];
  #pragma unroll
  for (int i = 0; i < 4; ++i)
    #pragma unroll
    for (int j = 0; j < 16; ++j) acc[i][j] = 0.f;

  for (int cc = 0; cc < CIN; cc += CK) {
    __syncthreads();
    for (int idx = tid; idx < CK * 324; idx += NT) {
      int c = idx / 324, rem = idx - c * 324;
      int iy = rem / 18, ix = rem - iy * 18;
      int gy = y0 - 1 + iy, gx = x0 - 1 + ix;
      float v = 0.f;
      if ((unsigned)gy < 64u && (unsigned)gx < 64u)
        v = in[(((size_t)b * CIN + cc + c) << 12) + (gy << 6) + gx];
      sIn[c][iy][ix] = v;
    }
    for (int idx = tid; idx < CK * 9 * CT; idx += NT) {
      int co = idx % CT;
      int rest = idx / CT;
      int tap = rest % 9, c = rest / 9;
      sW[c][tap][co] = wt[((size_t)(cc + c) * 9 + tap) * COUT + cog0 + co];
    }
    __syncthreads();
    #pragma unroll
    for (int c = 0; c < CK; ++c) {
      #pragma unroll
      for (int dy = 0; dy < 3; ++dy) {
        float r[6];
        #pragma unroll
        for (int j = 0; j < 6; ++j) r[j] = sIn[c][py + dy][px0 + j];
        #pragma unroll
        for (int dx = 0; dx < 3; ++dx) {
          float wv[16];
          #pragma unroll
          for (int j = 0; j < 16; ++j) wv[j] = sW[c][dy * 3 + dx][cg * 16 + j];
          #pragma unroll
          for (int i = 0; i < 4; ++i)
            #pragma unroll
            for (int j = 0; j < 16; ++j)
              acc[i][j] = fmaf(r[dx + i], wv[j], acc[i][j]);
        }
      }
    }
  }
  #pragma unroll
  for (int j = 0; j < 16; ++j) {
    int co = cog0 + cg * 16 + j;
    float sc = gamma[co] / sqrtf(1.0f + 1e-5f);
    float bb = bconv[co], sh = beta[co];
    #pragma unroll
    for (int i = 0; i < 4; ++i) {
      float v = (acc[i][j] + bb) * sc + sh;
      if (RELU) v = fmaxf(v, 0.f);
      out[(((size_t)b * COUT + co) << 12) + ((y0 + py) << 6) + (x0 + px0 + i)] = v;
    }
  }
}

// ---------------------------------------------------------------------------
// last conv (256->1) + BN (no relu) + the three 1x1 heads fused.
// ---------------------------------------------------------------------------
__global__ __launch_bounds__(256) void conv_l4_heads_kernel(
    const float* __restrict__ in,       // [nb][256][64][64]
    const float* __restrict__ w4,       // [256*9]
    const float* __restrict__ b4, const float* __restrict__ gm4,
    const float* __restrict__ bt4,
    const float* __restrict__ cw, const float* __restrict__ cb,
    const float* __restrict__ gw, const float* __restrict__ gb,
    const float* __restrict__ ow, const float* __restrict__ ob,
    float* __restrict__ costout,        // [16][4096]  (global batch index)
    float* __restrict__ geoout, float* __restrict__ obsout,  // d_out regions
    int b0)
{
  __shared__ float sIn[8][18][18];
  __shared__ float sW[8][9];
  const int tile = blockIdx.x, b = blockIdx.y;
  const int y0 = (tile >> 2) << 4, x0 = (tile & 3) << 4;
  const int tid = threadIdx.x;
  const int py = tid >> 4, px = tid & 15;
  float acc = 0.f;
  for (int cc = 0; cc < 256; cc += 8) {
    __syncthreads();
    for (int idx = tid; idx < 8 * 324; idx += 256) {
      int c = idx / 324, rem = idx - c * 324;
      int iy = rem / 18, ix = rem - iy * 18;
      int gy = y0 - 1 + iy, gx = x0 - 1 + ix;
      float v = 0.f;
      if ((unsigned)gy < 64u && (unsigned)gx < 64u)
        v = in[(((size_t)b * 256 + cc + c) << 12) + (gy << 6) + gx];
      sIn[c][iy][ix] = v;
    }
    if (tid < 72) sW[tid / 9][tid % 9] = w4[(cc + tid / 9) * 9 + tid % 9];
    __syncthreads();
    #pragma unroll
    for (int c = 0; c < 8; ++c)
      #pragma unroll
      for (int dy = 0; dy < 3; ++dy)
        #pragma unroll
        for (int dx = 0; dx < 3; ++dx)
          acc = fmaf(sIn[c][py + dy][px + dx], sW[c][dy * 3 + dx], acc);
  }
  float sc = gm4[0] / sqrtf(1.0f + 1e-5f);
  float f  = (acc + b4[0]) * sc + bt4[0];
  float cv = 1.f / (1.f + expf(-(f * cw[0] + cb[0])));
  float gv = fmaxf(f * gw[0] + gb[0], 0.f);
  float ov = fmaxf(f * ow[0] + ob[0], 0.f);
  int gbi = b0 + b;
  int pix = ((y0 + py) << 6) + (x0 + px);
  costout[gbi * HW + pix] = cv;
  geoout[gbi * HW + pix]  = gv;
  obsout[gbi * HW + pix]  = ov;
}

// ---------------------------------------------------------------------------
// A* pass 1 (restructured for critical-path latency):
//   - per-cell packed state cell[i] = {g, flag, h(+cost), cost} -> ONE
//     ds_read_b128 per neighbor instead of 3 serialized reads
//   - pk[i] = {fe, gc=g+cost}; gc is carried through the argmax butterfly so
//     g2 is available with ZERO memory reads after the reduce (no global
//     costm read, no g[ind] LDS read in the chain)
//   - rescan read of row r issued BEFORE the update writes (single wave ->
//     LDS in-order -> deterministic pre-update snapshot); monotone patches
//     (now including row r) make the result exact; one barrier per step
//   - fixpoint early-exit: once goal selected with no triggers, all later
//     steps are provably identical -> fill journal tail and break
// flag: 0=free, 1=open, 2=closed-or-obstacle
// ---------------------------------------------------------------------------
__global__ __launch_bounds__(64) void astar_pass1_kernel(
    const float* __restrict__ costm,
    const float* __restrict__ startm,
    const float* __restrict__ goalm,
    const float* __restrict__ mapd,
    unsigned short* __restrict__ Jmeta,   // [16][512]  ind | solved<<15
    unsigned short* __restrict__ Jcells)  // [16][512][8]
{
  __shared__ float4 cell[HW];   // g, flag, hs(=heur+cost), cost     (64 KB)
  __shared__ float2 pk[HW];     // fe, gc(=g+cost)                   (32 KB)
  const int b = blockIdx.x, lane = threadIdx.x;

  // goal index
  int gi = 0x7fffffff;
  for (int i = lane; i < HW; i += 64)
    if (goalm[b * HW + i] > 0.5f) gi = min(gi, i);
  #pragma unroll
  for (int m = 32; m; m >>= 1) gi = min(gi, __shfl_xor(gi, m));
  const int goal_idx = gi;
  const float gyf = (float)(goal_idx >> 6), gxf = (float)(goal_idx & 63);

  for (int i = lane; i < HW; i += 64) {
    float c_ = costm[b * HW + i];
    float iy = (float)(i >> 6), ix = (float)(i & 63);
    float d0 = fabsf(iy - gyf), d1 = fabsf(ix - gxf);
    float cheb = (d0 + d1) - fminf(d0, d1);
    float euc  = sqrtf(d0 * d0 + d1 * d1);
    float h = (cheb + 0.001f * euc) + c_;     // heuristic + cost (ref order)
    bool st = startm[b * HW + i] > 0.5f;
    float flg = st ? 1.f : ((mapd[b * HW + i] > 0.5f) ? 0.f : 2.f);
    cell[i] = make_float4(0.f, flg, h, c_);
    // f = 0.5*g + 0.5*h with g=0 -> 0.5*h ; exp(-f/8) with /8 exact as *0.125
    pk[i] = make_float2(st ? expf(-((0.5f * h) * 0.125f)) : 0.f, c_);
  }
  __syncthreads();

  // per-lane row registers: (max fe, first index, gc of that cell) of row `lane`
  float gm = -1.f; int gidx = 0; float ggc = 0.f;
  {
    int base = lane << 6;
    for (int k = 0; k < 64; ++k) {
      int ci = base + ((k + lane) & 63);
      float2 p = pk[ci];
      if (p.x > gm || (p.x == gm && ci < gidx)) { gm = p.x; gidx = ci; ggc = p.y; }
    }
  }

  int t = 0;
  for (; t < 512; ++t) {
    // ---- global argmax carrying (fe, idx, gc); first-index tie-break ----
    float v = gm; int idx = gidx; float gc = ggc;
    #pragma unroll
    for (int m = 32; m; m >>= 1) {
      float vo = __shfl_xor(v, m);
      int   io = __shfl_xor(idx, m);
      float co = __shfl_xor(gc, m);
      bool take = (vo > v) || (vo == v && io < idx);
      if (take) { v = vo; idx = io; gc = co; }
    }
    const int ind = idx;
    const float g2 = gc;                     // = g[ind] + cost[ind]
    const bool unsolved = (ind != goal_idx);
    const int r = ind >> 6, cx = ind & 63;

    // ---- rescan read issued EARLY: deterministic pre-update snapshot ----
    const int rb = (r << 6) + lane;
    float2 rp = pk[rb];

    // ---- neighbor updates (lanes 0..7), selected-cell close (lane 8) ----
    int pcell = -1; float pval = 0.f, pgc = 0.f;
    if (lane < 8) {
      int kk = (lane >= 4) ? lane + 1 : lane;        // skip center tap
      int ny = r + (kk / 3) - 1, nx = cx + (kk % 3) - 1;
      if ((unsigned)ny < 64u && (unsigned)nx < 64u) {
        int n = (ny << 6) + nx;
        float4 cd = cell[n];                 // one ds_read_b128
        bool trig = (cd.y == 1.f) ? (cd.x > g2) : (cd.y == 0.f);
        if (trig) {
          float fv = expf(-((0.5f * g2 + 0.5f * cd.z) * 0.125f));
          *(float2*)&cell[n] = make_float2(g2, 1.f);   // g, flag
          pk[n] = make_float2(fv, g2 + cd.w);          // fe, gc
          pcell = n; pval = fv; pgc = g2 + cd.w;
        }
      }
      Jcells[((size_t)b * 512 + t) * 8 + lane] =
          (unsigned short)(pcell >= 0 ? pcell : 0xFFFF);
    } else if (lane == 8) {
      if (unsolved) {
        cell[ind].y = 2.f;     // closed
        pk[ind].x  = 0.f;      // fe -> 0
      }
      Jmeta[b * 512 + t] = (unsigned short)(ind | (unsolved ? 0 : 0x8000));
    }

    // ---- rescan reduce over the pre-update snapshot (exclude ind if zeroed)
    float bv = (unsolved && lane == cx) ? -1.f : rp.x;
    int bi = rb; float bgc = rp.y;
    #pragma unroll
    for (int m = 32; m; m >>= 1) {
      float vo = __shfl_xor(bv, m);
      int   io = __shfl_xor(bi, m);
      float co = __shfl_xor(bgc, m);
      bool take = (vo > bv) || (vo == bv && io < bi);
      if (take) { bv = vo; bi = io; bgc = co; }
    }
    if (lane == r) { gm = bv; gidx = bi; ggc = bgc; }

    // ---- monotone-increase patches (all affected rows, incl. r) ----
    #pragma unroll
    for (int k = 0; k < 8; ++k) {
      int   pc = __shfl(pcell, k);
      float pv = __shfl(pval, k);
      float pg = __shfl(pgc, k);
      if (pc >= 0 && (pc >> 6) == lane) {
        if (pv > gm || (pv == gm && pc < gidx)) { gm = pv; gidx = pc; ggc = pg; }
      }
    }

    // ---- fixpoint: goal selected and nothing changed -> constant tail ----
    bool fixpoint = (!unsolved) && !__any(pcell >= 0);
    __syncthreads();
    if (fixpoint) { ++t; break; }
  }

  // fill remaining journal with the constant tail
  {
    unsigned short jm = (unsigned short)(goal_idx | 0x8000);
    uint4* jc4 = (uint4*)Jcells;
    for (int tt = t + lane; tt < 512; tt += 64) {
      Jmeta[b * 512 + tt] = jm;
      jc4[(size_t)b * 512 + tt] =
          make_uint4(0xFFFFFFFFu, 0xFFFFFFFFu, 0xFFFFFFFFu, 0xFFFFFFFFu);
    }
  }
}

// ---------------------------------------------------------------------------
// A* pass 2: t* = first t where all 16 batches selected their goal; replay
// journal for t<=t*, then backtrack.  One block (one wave) per batch.
// ---------------------------------------------------------------------------
__global__ __launch_bounds__(64) void astar_pass2_kernel(
    const unsigned short* __restrict__ Jmeta,
    const unsigned short* __restrict__ Jcells,
    const float* __restrict__ goalm,
    float* __restrict__ out_hist, float* __restrict__ out_path)
{
  __shared__ unsigned short par[HW];
  __shared__ unsigned short jm[64];
  __shared__ unsigned short jc[64][8];
  const int b = blockIdx.x, lane = threadIdx.x;

  for (int i = lane; i < HW; i += 64) {
    out_hist[b * HW + i] = 0.f;
    out_path[b * HW + i] = 0.f;
  }
  // t_last
  int localmin = 512;
  for (int t = lane; t < 512; t += 64) {
    bool all16 = true;
    for (int bb = 0; bb < 16; ++bb)
      all16 = all16 && ((Jmeta[bb * 512 + t] & 0x8000u) != 0);
    if (all16) localmin = min(localmin, t);
  }
  #pragma unroll
  for (int m = 32; m; m >>= 1) localmin = min(localmin, __shfl_xor(localmin, m));
  const int t_last = (localmin < 512) ? localmin : 511;

  // goal index
  int gi = 0x7fffffff;
  for (int i = lane; i < HW; i += 64)
    if (goalm[b * HW + i] > 0.5f) gi = min(gi, i);
  #pragma unroll
  for (int m = 32; m; m >>= 1) gi = min(gi, __shfl_xor(gi, m));

  for (int i = lane; i < HW; i += 64) par[i] = (unsigned short)gi;
  __syncthreads();

  // replay journal t = 0..t_last (inclusive)
  for (int t0 = 0; t0 <= t_last; t0 += 64) {
    if (t0 + lane < 512) {
      jm[lane] = Jmeta[b * 512 + t0 + lane];
      const unsigned short* src = &Jcells[((size_t)b * 512 + t0 + lane) * 8];
      #pragma unroll
      for (int k = 0; k < 8; ++k) jc[lane][k] = src[k];
    }
    __syncthreads();
    int te = min(t_last - t0, 63);
    for (int tt = 0; tt <= te; ++tt) {
      int ind = jm[tt] & 0x0FFF;
      if (lane < 8) {
        unsigned short c = jc[tt][lane];
        if (c != 0xFFFFu) par[c] = (unsigned short)ind;
      } else if (lane == 8) {
        out_hist[b * HW + ind] = 1.0f;
      }
    }
    __syncthreads();
  }
  // backtrack
  if (lane == 0) {
    out_path[b * HW + gi] = 1.0f;
    int loc = par[gi];
    for (int i = 0; i < t_last; ++i) {
      out_path[b * HW + loc] = 1.0f;
      loc = par[loc];
    }
  }
}

// ---------------------------------------------------------------------------
extern "C" void kernel_launch(void* const* d_in, const int* in_sizes, int n_in,
                              void* d_out, int out_size, void* d_ws, size_t ws_size,
                              hipStream_t stream)
{
  (void)in_sizes; (void)n_in; (void)out_size;
  const float* mapd   = (const float*)d_in[0];
  const float* startm = (const float*)d_in[1];
  const float* goalm  = (const float*)d_in[2];
  const float* w0 = (const float*)d_in[3];
  const float* b0 = (const float*)d_in[4];
  const float* gm0= (const float*)d_in[5];
  const float* bt0= (const float*)d_in[6];
  const float* w1 = (const float*)d_in[7];
  const float* b1 = (const float*)d_in[8];
  const float* gm1= (const float*)d_in[9];
  const float* bt1= (const float*)d_in[10];
  const float* w2 = (const float*)d_in[11];
  const float* b2 = (const float*)d_in[12];
  const float* gm2= (const float*)d_in[13];
  const float* bt2= (const float*)d_in[14];
  const float* w3 = (const float*)d_in[15];
  const float* b3 = (const float*)d_in[16];
  const float* gm3= (const float*)d_in[17];
  const float* bt3= (const float*)d_in[18];
  const float* w4 = (const float*)d_in[19];
  const float* b4 = (const float*)d_in[20];
  const float* gm4= (const float*)d_in[21];
  const float* bt4= (const float*)d_in[22];
  const float* cw = (const float*)d_in[23];
  const float* cb = (const float*)d_in[24];
  const float* gw = (const float*)d_in[25];
  const float* gb = (const float*)d_in[26];
  const float* owp= (const float*)d_in[27];
  const float* obp= (const float*)d_in[28];
  float* out = (float*)d_out;

  float* wsf = (float*)d_ws;
  size_t off = 0;
  auto alloc = [&](size_t n) { float* p = wsf + off; off += n; return p; };
  float* wt0 = alloc(3 * 9 * 32);
  float* wt1 = alloc(32 * 9 * 64);
  float* wt2 = alloc(64 * 9 * 128);
  float* wt3 = alloc(128 * 9 * 256);
  float* in3   = alloc(16 * 3 * HW);
  float* costb = alloc(16 * HW);
  unsigned short* Jmeta  = (unsigned short*)alloc(16 * 512 / 2);
  unsigned short* Jcells = (unsigned short*)alloc(16 * 512 * 8 / 2);
  size_t fixed = off;

  // conv batch-group size: largest G whose ping-pong buffers fit the workspace
  int G = 16;
  while (G > 1 && (fixed + (size_t)G * 1572864ull) * sizeof(float) > ws_size) G >>= 1;
  float* bufA = alloc((size_t)G * 524288);    // up to 128 ch per batch
  float* bufB = alloc((size_t)G * 1048576);   // up to 256 ch per batch

  pack3_kernel<<<(16 * 3 * HW + 255) / 256, 256, 0, stream>>>(mapd, startm, goalm, in3);
  wtrans_kernel<<<(3 * 9 * 32 + 255) / 256, 256, 0, stream>>>(w0, wt0, 3, 32);
  wtrans_kernel<<<(32 * 9 * 64 + 255) / 256, 256, 0, stream>>>(w1, wt1, 32, 64);
  wtrans_kernel<<<(64 * 9 * 128 + 255) / 256, 256, 0, stream>>>(w2, wt2, 64, 128);
  wtrans_kernel<<<(128 * 9 * 256 + 255) / 256, 256, 0, stream>>>(w3, wt3, 128, 256);

  for (int g0 = 0; g0 < 16; g0 += G) {
    conv3x3_kernel<3, 32, 3, true><<<dim3(16, 1, G), 128, 0, stream>>>(
        in3 + (size_t)g0 * 3 * HW, bufA, wt0, b0, gm0, bt0);
    conv3x3_kernel<32, 64, 8, true><<<dim3(16, 1, G), 256, 0, stream>>>(
        bufA, bufB, wt1, b1, gm1, bt1);
    conv3x3_kernel<64, 128, 8, true><<<dim3(16, 2, G), 256, 0, stream>>>(
        bufB, bufA, wt2, b2, gm2, bt2);
    conv3x3_kernel<128, 256, 8, true><<<dim3(16, 4, G), 256, 0, stream>>>(
        bufA, bufB, wt3, b3, gm3, bt3);
    conv_l4_heads_kernel<<<dim3(16, G), 256, 0, stream>>>(
        bufB, w4, b4, gm4, bt4, cw, cb, gw, gb, owp, obp,
        costb, out + 2 * 16 * HW, out + 3 * 16 * HW, g0);
  }

  astar_pass1_kernel<<<16, 64, 0, stream>>>(costb, startm, goalm, mapd, Jmeta, Jcells);
  astar_pass2_kernel<<<16, 64, 0, stream>>>(Jmeta, Jcells, goalm, out, out + 16 * HW);
}

// Round 3
// 1042.446 us; speedup vs baseline: 1.9161x; 1.1250x over previous
//
#include <hip/hip_runtime.h>

#define HW 4096

// ---------------------------------------------------------------------------
// pack [map, start, goal] -> [16][3][64][64]
// ---------------------------------------------------------------------------
__global__ __launch_bounds__(256) void pack3_kernel(
    const float* __restrict__ m, const float* __restrict__ s,
    const float* __restrict__ g, float* __restrict__ in3)
{
  int idx = blockIdx.x * 256 + threadIdx.x;
  if (idx >= 16 * 3 * HW) return;
  int p = idx & (HW - 1);
  int bc = idx >> 12;
  int c = bc % 3, b = bc / 3;
  const float* src = (c == 0) ? m : ((c == 1) ? s : g);
  in3[idx] = src[b * HW + p];
}

// ---------------------------------------------------------------------------
// weight transpose: w[co][c][3][3] -> wt[(c*9+tap)][co]   (coalesced staging)
// ---------------------------------------------------------------------------
__global__ __launch_bounds__(256) void wtrans_kernel(
    const float* __restrict__ w, float* __restrict__ wt, int cin, int cout)
{
  int idx = blockIdx.x * 256 + threadIdx.x;
  int total = cin * 9 * cout;
  if (idx >= total) return;
  int co = idx % cout;
  int rest = idx / cout;              // c*9+tap
  wt[idx] = w[co * cin * 9 + rest];
}

// ---------------------------------------------------------------------------
// direct 3x3 conv + bias + BN(eval) + optional ReLU.  16x16 spatial tile,
// CT<=64 output channels per block; thread = 4 pixels x 16 couts.
// Row stride padded to 20 floats: 16B-aligned rows -> ds_read_b128 input
// reads, uniform bank spread; weights read as wave-uniform b128 broadcasts.
// c-loop deliberately NOT unrolled (I$); launch_bounds(,2) frees VGPRs for
// software pipelining.
// ---------------------------------------------------------------------------
template<int CIN, int COUT, int CK, bool RELU>
__global__ __launch_bounds__(((COUT < 64) ? COUT : 64) * 4, 2)
void conv3x3_kernel(
    const float* __restrict__ in,    // [nb][CIN][64][64]
    float* __restrict__ out,         // [nb][COUT][64][64]
    const float* __restrict__ wt,    // [(c*9+tap)][COUT]
    const float* __restrict__ bconv,
    const float* __restrict__ gamma, const float* __restrict__ beta)
{
  constexpr int CT  = (COUT < 64) ? COUT : 64;
  constexpr int NCG = CT / 16;
  constexpr int NT  = 64 * NCG;
  __shared__ float sIn[CK][18][20];
  __shared__ float sW[CK][9][CT];
  const int tile = blockIdx.x;
  const int cog0 = blockIdx.y * CT;
  const int b    = blockIdx.z;
  const int y0 = (tile >> 2) << 4, x0 = (tile & 3) << 4;
  const int tid = threadIdx.x;
  const int cg = tid >> 6;
  const int pg = tid & 63;
  const int py = pg >> 2, px0 = (pg & 3) << 2;

  float acc[4][16];
  #pragma unroll
  for (int i = 0; i < 4; ++i)
    #pragma unroll
    for (int j = 0; j < 16; ++j) acc[i][j] = 0.f;

  for (int cc = 0; cc < CIN; cc += CK) {
    __syncthreads();
    for (int idx = tid; idx < CK * 324; idx += NT) {
      int c = idx / 324, rem = idx - c * 324;
      int iy = rem / 18, ix = rem - iy * 18;
      int gy = y0 - 1 + iy, gx = x0 - 1 + ix;
      float v = 0.f;
      if ((unsigned)gy < 64u && (unsigned)gx < 64u)
        v = in[(((size_t)b * CIN + cc + c) << 12) + (gy << 6) + gx];
      sIn[c][iy][ix] = v;
    }
    for (int idx = tid; idx < CK * 9 * CT; idx += NT) {
      int co = idx % CT;
      int rest = idx / CT;
      int tap = rest % 9, c = rest / 9;
      sW[c][tap][co] = wt[((size_t)(cc + c) * 9 + tap) * COUT + cog0 + co];
    }
    __syncthreads();
    for (int c = 0; c < CK; ++c) {
      #pragma unroll
      for (int dy = 0; dy < 3; ++dy) {
        const float* rowp = &sIn[c][py + dy][px0];      // 16B aligned
        float4 ra = *(const float4*)rowp;
        float4 rb = *(const float4*)(rowp + 4);
        float r[6] = {ra.x, ra.y, ra.z, ra.w, rb.x, rb.y};
        #pragma unroll
        for (int dx = 0; dx < 3; ++dx) {
          const float4* wp = (const float4*)&sW[c][dy * 3 + dx][cg * 16];
          float4 w0 = wp[0], w1 = wp[1], w2 = wp[2], w3 = wp[3];
          float wv[16] = {w0.x, w0.y, w0.z, w0.w, w1.x, w1.y, w1.z, w1.w,
                          w2.x, w2.y, w2.z, w2.w, w3.x, w3.y, w3.z, w3.w};
          #pragma unroll
          for (int i = 0; i < 4; ++i)
            #pragma unroll
            for (int j = 0; j < 16; ++j)
              acc[i][j] = fmaf(r[dx + i], wv[j], acc[i][j]);
        }
      }
    }
  }
  #pragma unroll
  for (int j = 0; j < 16; ++j) {
    int co = cog0 + cg * 16 + j;
    float sc = gamma[co] / sqrtf(1.0f + 1e-5f);
    float bb = bconv[co], sh = beta[co];
    #pragma unroll
    for (int i = 0; i < 4; ++i) {
      float v = (acc[i][j] + bb) * sc + sh;
      if (RELU) v = fmaxf(v, 0.f);
      out[(((size_t)b * COUT + co) << 12) + ((y0 + py) << 6) + (x0 + px0 + i)] = v;
    }
  }
}

// ---------------------------------------------------------------------------
// last conv (256->1) + BN (no relu) + the three 1x1 heads fused.
// ---------------------------------------------------------------------------
__global__ __launch_bounds__(256) void conv_l4_heads_kernel(
    const float* __restrict__ in,       // [nb][256][64][64]
    const float* __restrict__ w4,       // [256*9]
    const float* __restrict__ b4, const float* __restrict__ gm4,
    const float* __restrict__ bt4,
    const float* __restrict__ cw, const float* __restrict__ cb,
    const float* __restrict__ gw, const float* __restrict__ gb,
    const float* __restrict__ ow, const float* __restrict__ ob,
    float* __restrict__ costout,        // [16][4096]  (global batch index)
    float* __restrict__ geoout, float* __restrict__ obsout,  // d_out regions
    int b0)
{
  __shared__ float sIn[8][18][20];
  __shared__ float sW[8][9];
  const int tile = blockIdx.x, b = blockIdx.y;
  const int y0 = (tile >> 2) << 4, x0 = (tile & 3) << 4;
  const int tid = threadIdx.x;
  const int py = tid >> 4, px = tid & 15;
  float acc = 0.f;
  for (int cc = 0; cc < 256; cc += 8) {
    __syncthreads();
    for (int idx = tid; idx < 8 * 324; idx += 256) {
      int c = idx / 324, rem = idx - c * 324;
      int iy = rem / 18, ix = rem - iy * 18;
      int gy = y0 - 1 + iy, gx = x0 - 1 + ix;
      float v = 0.f;
      if ((unsigned)gy < 64u && (unsigned)gx < 64u)
        v = in[(((size_t)b * 256 + cc + c) << 12) + (gy << 6) + gx];
      sIn[c][iy][ix] = v;
    }
    if (tid < 72) sW[tid / 9][tid % 9] = w4[(cc + tid / 9) * 9 + tid % 9];
    __syncthreads();
    #pragma unroll
    for (int c = 0; c < 8; ++c)
      #pragma unroll
      for (int dy = 0; dy < 3; ++dy)
        #pragma unroll
        for (int dx = 0; dx < 3; ++dx)
          acc = fmaf(sIn[c][py + dy][px + dx], sW[c][dy * 3 + dx], acc);
  }
  float sc = gm4[0] / sqrtf(1.0f + 1e-5f);
  float f  = (acc + b4[0]) * sc + bt4[0];
  float cv = 1.f / (1.f + expf(-(f * cw[0] + cb[0])));
  float gv = fmaxf(f * gw[0] + gb[0], 0.f);
  float ov = fmaxf(f * ow[0] + ob[0], 0.f);
  int gbi = b0 + b;
  int pix = ((y0 + py) << 6) + (x0 + px);
  costout[gbi * HW + pix] = cv;
  geoout[gbi * HW + pix]  = gv;
  obsout[gbi * HW + pix]  = ov;
}

// ---------------------------------------------------------------------------
// A* pass 1 (unchanged from round 2 -- proven correct & fast)
// ---------------------------------------------------------------------------
__global__ __launch_bounds__(64) void astar_pass1_kernel(
    const float* __restrict__ costm,
    const float* __restrict__ startm,
    const float* __restrict__ goalm,
    const float* __restrict__ mapd,
    unsigned short* __restrict__ Jmeta,   // [16][512]  ind | solved<<15
    unsigned short* __restrict__ Jcells)  // [16][512][8]
{
  __shared__ float4 cell[HW];   // g, flag, hs(=heur+cost), cost     (64 KB)
  __shared__ float2 pk[HW];     // fe, gc(=g+cost)                   (32 KB)
  const int b = blockIdx.x, lane = threadIdx.x;

  int gi = 0x7fffffff;
  for (int i = lane; i < HW; i += 64)
    if (goalm[b * HW + i] > 0.5f) gi = min(gi, i);
  #pragma unroll
  for (int m = 32; m; m >>= 1) gi = min(gi, __shfl_xor(gi, m));
  const int goal_idx = gi;
  const float gyf = (float)(goal_idx >> 6), gxf = (float)(goal_idx & 63);

  for (int i = lane; i < HW; i += 64) {
    float c_ = costm[b * HW + i];
    float iy = (float)(i >> 6), ix = (float)(i & 63);
    float d0 = fabsf(iy - gyf), d1 = fabsf(ix - gxf);
    float cheb = (d0 + d1) - fminf(d0, d1);
    float euc  = sqrtf(d0 * d0 + d1 * d1);
    float h = (cheb + 0.001f * euc) + c_;
    bool st = startm[b * HW + i] > 0.5f;
    float flg = st ? 1.f : ((mapd[b * HW + i] > 0.5f) ? 0.f : 2.f);
    cell[i] = make_float4(0.f, flg, h, c_);
    pk[i] = make_float2(st ? expf(-((0.5f * h) * 0.125f)) : 0.f, c_);
  }
  __syncthreads();

  float gm = -1.f; int gidx = 0; float ggc = 0.f;
  {
    int base = lane << 6;
    for (int k = 0; k < 64; ++k) {
      int ci = base + ((k + lane) & 63);
      float2 p = pk[ci];
      if (p.x > gm || (p.x == gm && ci < gidx)) { gm = p.x; gidx = ci; ggc = p.y; }
    }
  }

  int t = 0;
  for (; t < 512; ++t) {
    float v = gm; int idx = gidx; float gc = ggc;
    #pragma unroll
    for (int m = 32; m; m >>= 1) {
      float vo = __shfl_xor(v, m);
      int   io = __shfl_xor(idx, m);
      float co = __shfl_xor(gc, m);
      bool take = (vo > v) || (vo == v && io < idx);
      if (take) { v = vo; idx = io; gc = co; }
    }
    const int ind = idx;
    const float g2 = gc;
    const bool unsolved = (ind != goal_idx);
    const int r = ind >> 6, cx = ind & 63;

    const int rb = (r << 6) + lane;
    float2 rp = pk[rb];

    int pcell = -1; float pval = 0.f, pgc = 0.f;
    if (lane < 8) {
      int kk = (lane >= 4) ? lane + 1 : lane;
      int ny = r + (kk / 3) - 1, nx = cx + (kk % 3) - 1;
      if ((unsigned)ny < 64u && (unsigned)nx < 64u) {
        int n = (ny << 6) + nx;
        float4 cd = cell[n];
        bool trig = (cd.y == 1.f) ? (cd.x > g2) : (cd.y == 0.f);
        if (trig) {
          float fv = expf(-((0.5f * g2 + 0.5f * cd.z) * 0.125f));
          *(float2*)&cell[n] = make_float2(g2, 1.f);
          pk[n] = make_float2(fv, g2 + cd.w);
          pcell = n; pval = fv; pgc = g2 + cd.w;
        }
      }
      Jcells[((size_t)b * 512 + t) * 8 + lane] =
          (unsigned short)(pcell >= 0 ? pcell : 0xFFFF);
    } else if (lane == 8) {
      if (unsolved) {
        cell[ind].y = 2.f;
        pk[ind].x  = 0.f;
      }
      Jmeta[b * 512 + t] = (unsigned short)(ind | (unsolved ? 0 : 0x8000));
    }

    float bv = (unsolved && lane == cx) ? -1.f : rp.x;
    int bi = rb; float bgc = rp.y;
    #pragma unroll
    for (int m = 32; m; m >>= 1) {
      float vo = __shfl_xor(bv, m);
      int   io = __shfl_xor(bi, m);
      float co = __shfl_xor(bgc, m);
      bool take = (vo > bv) || (vo == bv && io < bi);
      if (take) { bv = vo; bi = io; bgc = co; }
    }
    if (lane == r) { gm = bv; gidx = bi; ggc = bgc; }

    #pragma unroll
    for (int k = 0; k < 8; ++k) {
      int   pc = __shfl(pcell, k);
      float pv = __shfl(pval, k);
      float pg = __shfl(pgc, k);
      if (pc >= 0 && (pc >> 6) == lane) {
        if (pv > gm || (pv == gm && pc < gidx)) { gm = pv; gidx = pc; ggc = pg; }
      }
    }

    bool fixpoint = (!unsolved) && !__any(pcell >= 0);
    __syncthreads();
    if (fixpoint) { ++t; break; }
  }

  {
    unsigned short jm = (unsigned short)(goal_idx | 0x8000);
    uint4* jc4 = (uint4*)Jcells;
    for (int tt = t + lane; tt < 512; tt += 64) {
      Jmeta[b * 512 + tt] = jm;
      jc4[(size_t)b * 512 + tt] =
          make_uint4(0xFFFFFFFFu, 0xFFFFFFFFu, 0xFFFFFFFFu, 0xFFFFFFFFu);
    }
  }
}

// ---------------------------------------------------------------------------
// A* pass 2 (unchanged)
// ---------------------------------------------------------------------------
__global__ __launch_bounds__(64) void astar_pass2_kernel(
    const unsigned short* __restrict__ Jmeta,
    const unsigned short* __restrict__ Jcells,
    const float* __restrict__ goalm,
    float* __restrict__ out_hist, float* __restrict__ out_path)
{
  __shared__ unsigned short par[HW];
  __shared__ unsigned short jm[64];
  __shared__ unsigned short jc[64][8];
  const int b = blockIdx.x, lane = threadIdx.x;

  for (int i = lane; i < HW; i += 64) {
    out_hist[b * HW + i] = 0.f;
    out_path[b * HW + i] = 0.f;
  }
  int localmin = 512;
  for (int t = lane; t < 512; t += 64) {
    bool all16 = true;
    for (int bb = 0; bb < 16; ++bb)
      all16 = all16 && ((Jmeta[bb * 512 + t] & 0x8000u) != 0);
    if (all16) localmin = min(localmin, t);
  }
  #pragma unroll
  for (int m = 32; m; m >>= 1) localmin = min(localmin, __shfl_xor(localmin, m));
  const int t_last = (localmin < 512) ? localmin : 511;

  int gi = 0x7fffffff;
  for (int i = lane; i < HW; i += 64)
    if (goalm[b * HW + i] > 0.5f) gi = min(gi, i);
  #pragma unroll
  for (int m = 32; m; m >>= 1) gi = min(gi, __shfl_xor(gi, m));

  for (int i = lane; i < HW; i += 64) par[i] = (unsigned short)gi;
  __syncthreads();

  for (int t0 = 0; t0 <= t_last; t0 += 64) {
    if (t0 + lane < 512) {
      jm[lane] = Jmeta[b * 512 + t0 + lane];
      const unsigned short* src = &Jcells[((size_t)b * 512 + t0 + lane) * 8];
      #pragma unroll
      for (int k = 0; k < 8; ++k) jc[lane][k] = src[k];
    }
    __syncthreads();
    int te = min(t_last - t0, 63);
    for (int tt = 0; tt <= te; ++tt) {
      int ind = jm[tt] & 0x0FFF;
      if (lane < 8) {
        unsigned short c = jc[tt][lane];
        if (c != 0xFFFFu) par[c] = (unsigned short)ind;
      } else if (lane == 8) {
        out_hist[b * HW + ind] = 1.0f;
      }
    }
    __syncthreads();
  }
  if (lane == 0) {
    out_path[b * HW + gi] = 1.0f;
    int loc = par[gi];
    for (int i = 0; i < t_last; ++i) {
      out_path[b * HW + loc] = 1.0f;
      loc = par[loc];
    }
  }
}

// ---------------------------------------------------------------------------
extern "C" void kernel_launch(void* const* d_in, const int* in_sizes, int n_in,
                              void* d_out, int out_size, void* d_ws, size_t ws_size,
                              hipStream_t stream)
{
  (void)in_sizes; (void)n_in; (void)out_size;
  const float* mapd   = (const float*)d_in[0];
  const float* startm = (const float*)d_in[1];
  const float* goalm  = (const float*)d_in[2];
  const float* w0 = (const float*)d_in[3];
  const float* b0 = (const float*)d_in[4];
  const float* gm0= (const float*)d_in[5];
  const float* bt0= (const float*)d_in[6];
  const float* w1 = (const float*)d_in[7];
  const float* b1 = (const float*)d_in[8];
  const float* gm1= (const float*)d_in[9];
  const float* bt1= (const float*)d_in[10];
  const float* w2 = (const float*)d_in[11];
  const float* b2 = (const float*)d_in[12];
  const float* gm2= (const float*)d_in[13];
  const float* bt2= (const float*)d_in[14];
  const float* w3 = (const float*)d_in[15];
  const float* b3 = (const float*)d_in[16];
  const float* gm3= (const float*)d_in[17];
  const float* bt3= (const float*)d_in[18];
  const float* w4 = (const float*)d_in[19];
  const float* b4 = (const float*)d_in[20];
  const float* gm4= (const float*)d_in[21];
  const float* bt4= (const float*)d_in[22];
  const float* cw = (const float*)d_in[23];
  const float* cb = (const float*)d_in[24];
  const float* gw = (const float*)d_in[25];
  const float* gb = (const float*)d_in[26];
  const float* owp= (const float*)d_in[27];
  const float* obp= (const float*)d_in[28];
  float* out = (float*)d_out;

  float* wsf = (float*)d_ws;
  size_t off = 0;
  auto alloc = [&](size_t n) { float* p = wsf + off; off += n; return p; };
  float* wt0 = alloc(3 * 9 * 32);
  float* wt1 = alloc(32 * 9 * 64);
  float* wt2 = alloc(64 * 9 * 128);
  float* wt3 = alloc(128 * 9 * 256);
  float* in3   = alloc(16 * 3 * HW);
  float* costb = alloc(16 * HW);
  unsigned short* Jmeta  = (unsigned short*)alloc(16 * 512 / 2);
  unsigned short* Jcells = (unsigned short*)alloc(16 * 512 * 8 / 2);
  size_t fixed = off;

  // conv batch-group size: largest G whose ping-pong buffers fit the workspace
  int G = 16;
  while (G > 1 && (fixed + (size_t)G * 1572864ull) * sizeof(float) > ws_size) G >>= 1;
  float* bufA = alloc((size_t)G * 524288);    // up to 128 ch per batch
  float* bufB = alloc((size_t)G * 1048576);   // up to 256 ch per batch

  pack3_kernel<<<(16 * 3 * HW + 255) / 256, 256, 0, stream>>>(mapd, startm, goalm, in3);
  wtrans_kernel<<<(3 * 9 * 32 + 255) / 256, 256, 0, stream>>>(w0, wt0, 3, 32);
  wtrans_kernel<<<(32 * 9 * 64 + 255) / 256, 256, 0, stream>>>(w1, wt1, 32, 64);
  wtrans_kernel<<<(64 * 9 * 128 + 255) / 256, 256, 0, stream>>>(w2, wt2, 64, 128);
  wtrans_kernel<<<(128 * 9 * 256 + 255) / 256, 256, 0, stream>>>(w3, wt3, 128, 256);

  for (int g0 = 0; g0 < 16; g0 += G) {
    conv3x3_kernel<3, 32, 3, true><<<dim3(16, 1, G), 128, 0, stream>>>(
        in3 + (size_t)g0 * 3 * HW, bufA, wt0, b0, gm0, bt0);
    conv3x3_kernel<32, 64, 8, true><<<dim3(16, 1, G), 256, 0, stream>>>(
        bufA, bufB, wt1, b1, gm1, bt1);
    conv3x3_kernel<64, 128, 8, true><<<dim3(16, 2, G), 256, 0, stream>>>(
        bufB, bufA, wt2, b2, gm2, bt2);
    conv3x3_kernel<128, 256, 16, true><<<dim3(16, 4, G), 256, 0, stream>>>(
        bufA, bufB, wt3, b3, gm3, bt3);
    conv_l4_heads_kernel<<<dim3(16, G), 256, 0, stream>>>(
        bufB, w4, b4, gm4, bt4, cw, cb, gw, gb, owp, obp,
        costb, out + 2 * 16 * HW, out + 3 * 16 * HW, g0);
  }

  astar_pass1_kernel<<<16, 64, 0, stream>>>(costb, startm, goalm, mapd, Jmeta, Jcells);
  astar_pass2_kernel<<<16, 64, 0, stream>>>(Jmeta, Jcells, goalm, out, out + 16 * HW);
}

// Round 4
// 987.944 us; speedup vs baseline: 2.0219x; 1.0552x over previous
//
#include <hip/hip_runtime.h>

#define HW 4096

// ---------------------------------------------------------------------------
// pack [map, start, goal] -> [16][3][64][64]
// ---------------------------------------------------------------------------
__global__ __launch_bounds__(256) void pack3_kernel(
    const float* __restrict__ m, const float* __restrict__ s,
    const float* __restrict__ g, float* __restrict__ in3)
{
  int idx = blockIdx.x * 256 + threadIdx.x;
  if (idx >= 16 * 3 * HW) return;
  int p = idx & (HW - 1);
  int bc = idx >> 12;
  int c = bc % 3, b = bc / 3;
  const float* src = (c == 0) ? m : ((c == 1) ? s : g);
  in3[idx] = src[b * HW + p];
}

// ---------------------------------------------------------------------------
// weight transpose: w[co][c][3][3] -> wt[(c*9+tap)][co]   (coalesced staging)
// ---------------------------------------------------------------------------
__global__ __launch_bounds__(256) void wtrans_kernel(
    const float* __restrict__ w, float* __restrict__ wt, int cin, int cout)
{
  int idx = blockIdx.x * 256 + threadIdx.x;
  int total = cin * 9 * cout;
  if (idx >= total) return;
  int co = idx % cout;
  int rest = idx / cout;              // c*9+tap
  wt[idx] = w[co * cin * 9 + rest];
}

// ---------------------------------------------------------------------------
// direct 3x3 conv + bias + BN(eval) + optional ReLU.  16x16 spatial tile.
// thread = 4 pixels x CO_T couts; NT = 64 * (CT/CO_T).
// Row stride padded to 20 floats: 16B-aligned -> ds_read_b128 input reads;
// weights read as wave-uniform b128 broadcasts.  CK=8 keeps LDS ~30KB so
// 4 blocks/CU fit; launch_bounds(,4) caps VGPR at 128 for 4 waves/SIMD.
// ---------------------------------------------------------------------------
template<int CIN, int COUT, int CK, int CT, int CO_T, bool RELU>
__global__ __launch_bounds__(64 * (CT / CO_T), 4)
void conv3x3_kernel(
    const float* __restrict__ in,    // [nb][CIN][64][64]
    float* __restrict__ out,         // [nb][COUT][64][64]
    const float* __restrict__ wt,    // [(c*9+tap)][COUT]
    const float* __restrict__ bconv,
    const float* __restrict__ gamma, const float* __restrict__ beta)
{
  constexpr int NCG = CT / CO_T;
  constexpr int NT  = 64 * NCG;
  __shared__ float sIn[CK][18][20];
  __shared__ float sW[CK][9][CT];
  const int tile = blockIdx.x;
  const int cog0 = blockIdx.y * CT;
  const int b    = blockIdx.z;
  const int y0 = (tile >> 2) << 4, x0 = (tile & 3) << 4;
  const int tid = threadIdx.x;
  const int cg = tid >> 6;
  const int pg = tid & 63;
  const int py = pg >> 2, px0 = (pg & 3) << 2;

  float acc[4][CO_T];
  #pragma unroll
  for (int i = 0; i < 4; ++i)
    #pragma unroll
    for (int j = 0; j < CO_T; ++j) acc[i][j] = 0.f;

  for (int cc = 0; cc < CIN; cc += CK) {
    __syncthreads();
    for (int idx = tid; idx < CK * 324; idx += NT) {
      int c = idx / 324, rem = idx - c * 324;
      int iy = rem / 18, ix = rem - iy * 18;
      int gy = y0 - 1 + iy, gx = x0 - 1 + ix;
      float v = 0.f;
      if ((unsigned)gy < 64u && (unsigned)gx < 64u)
        v = in[(((size_t)b * CIN + cc + c) << 12) + (gy << 6) + gx];
      sIn[c][iy][ix] = v;
    }
    for (int idx = tid; idx < CK * 9 * CT; idx += NT) {
      int co = idx % CT;
      int rest = idx / CT;
      int tap = rest % 9, c = rest / 9;
      sW[c][tap][co] = wt[((size_t)(cc + c) * 9 + tap) * COUT + cog0 + co];
    }
    __syncthreads();
    for (int c = 0; c < CK; ++c) {
      #pragma unroll
      for (int dy = 0; dy < 3; ++dy) {
        const float* rowp = &sIn[c][py + dy][px0];      // 16B aligned
        float4 ra = *(const float4*)rowp;
        float4 rb = *(const float4*)(rowp + 4);
        float r[6] = {ra.x, ra.y, ra.z, ra.w, rb.x, rb.y};
        #pragma unroll
        for (int dx = 0; dx < 3; ++dx) {
          const float4* wp = (const float4*)&sW[c][dy * 3 + dx][cg * CO_T];
          float wv[CO_T];
          #pragma unroll
          for (int q = 0; q < CO_T / 4; ++q) {
            float4 w4 = wp[q];
            wv[q * 4 + 0] = w4.x; wv[q * 4 + 1] = w4.y;
            wv[q * 4 + 2] = w4.z; wv[q * 4 + 3] = w4.w;
          }
          #pragma unroll
          for (int i = 0; i < 4; ++i)
            #pragma unroll
            for (int j = 0; j < CO_T; ++j)
              acc[i][j] = fmaf(r[dx + i], wv[j], acc[i][j]);
        }
      }
    }
  }
  #pragma unroll
  for (int j = 0; j < CO_T; ++j) {
    int co = cog0 + cg * CO_T + j;
    float sc = gamma[co] / sqrtf(1.0f + 1e-5f);
    float bb = bconv[co], sh = beta[co];
    #pragma unroll
    for (int i = 0; i < 4; ++i) {
      float v = (acc[i][j] + bb) * sc + sh;
      if (RELU) v = fmaxf(v, 0.f);
      out[(((size_t)b * COUT + co) << 12) + ((y0 + py) << 6) + (x0 + px0 + i)] = v;
    }
  }
}

// ---------------------------------------------------------------------------
// last conv (256->1) + BN (no relu) + the three 1x1 heads fused.
// ---------------------------------------------------------------------------
__global__ __launch_bounds__(256) void conv_l4_heads_kernel(
    const float* __restrict__ in,       // [nb][256][64][64]
    const float* __restrict__ w4,       // [256*9]
    const float* __restrict__ b4, const float* __restrict__ gm4,
    const float* __restrict__ bt4,
    const float* __restrict__ cw, const float* __restrict__ cb,
    const float* __restrict__ gw, const float* __restrict__ gb,
    const float* __restrict__ ow, const float* __restrict__ ob,
    float* __restrict__ costout,        // [16][4096]  (global batch index)
    float* __restrict__ geoout, float* __restrict__ obsout,  // d_out regions
    int b0)
{
  __shared__ float sIn[8][18][20];
  __shared__ float sW[8][9];
  const int tile = blockIdx.x, b = blockIdx.y;
  const int y0 = (tile >> 2) << 4, x0 = (tile & 3) << 4;
  const int tid = threadIdx.x;
  const int py = tid >> 4, px = tid & 15;
  float acc = 0.f;
  for (int cc = 0; cc < 256; cc += 8) {
    __syncthreads();
    for (int idx = tid; idx < 8 * 324; idx += 256) {
      int c = idx / 324, rem = idx - c * 324;
      int iy = rem / 18, ix = rem - iy * 18;
      int gy = y0 - 1 + iy, gx = x0 - 1 + ix;
      float v = 0.f;
      if ((unsigned)gy < 64u && (unsigned)gx < 64u)
        v = in[(((size_t)b * 256 + cc + c) << 12) + (gy << 6) + gx];
      sIn[c][iy][ix] = v;
    }
    if (tid < 72) sW[tid / 9][tid % 9] = w4[(cc + tid / 9) * 9 + tid % 9];
    __syncthreads();
    #pragma unroll
    for (int c = 0; c < 8; ++c)
      #pragma unroll
      for (int dy = 0; dy < 3; ++dy)
        #pragma unroll
        for (int dx = 0; dx < 3; ++dx)
          acc = fmaf(sIn[c][py + dy][px + dx], sW[c][dy * 3 + dx], acc);
  }
  float sc = gm4[0] / sqrtf(1.0f + 1e-5f);
  float f  = (acc + b4[0]) * sc + bt4[0];
  float cv = 1.f / (1.f + expf(-(f * cw[0] + cb[0])));
  float gv = fmaxf(f * gw[0] + gb[0], 0.f);
  float ov = fmaxf(f * ow[0] + ob[0], 0.f);
  int gbi = b0 + b;
  int pix = ((y0 + py) << 6) + (x0 + px);
  costout[gbi * HW + pix] = cv;
  geoout[gbi * HW + pix]  = gv;
  obsout[gbi * HW + pix]  = ov;
}

// ---------------------------------------------------------------------------
// A* pass 1 (unchanged -- proven correct & fast)
// ---------------------------------------------------------------------------
__global__ __launch_bounds__(64) void astar_pass1_kernel(
    const float* __restrict__ costm,
    const float* __restrict__ startm,
    const float* __restrict__ goalm,
    const float* __restrict__ mapd,
    unsigned short* __restrict__ Jmeta,   // [16][512]  ind | solved<<15
    unsigned short* __restrict__ Jcells)  // [16][512][8]
{
  __shared__ float4 cell[HW];   // g, flag, hs(=heur+cost), cost     (64 KB)
  __shared__ float2 pk[HW];     // fe, gc(=g+cost)                   (32 KB)
  const int b = blockIdx.x, lane = threadIdx.x;

  int gi = 0x7fffffff;
  for (int i = lane; i < HW; i += 64)
    if (goalm[b * HW + i] > 0.5f) gi = min(gi, i);
  #pragma unroll
  for (int m = 32; m; m >>= 1) gi = min(gi, __shfl_xor(gi, m));
  const int goal_idx = gi;
  const float gyf = (float)(goal_idx >> 6), gxf = (float)(goal_idx & 63);

  for (int i = lane; i < HW; i += 64) {
    float c_ = costm[b * HW + i];
    float iy = (float)(i >> 6), ix = (float)(i & 63);
    float d0 = fabsf(iy - gyf), d1 = fabsf(ix - gxf);
    float cheb = (d0 + d1) - fminf(d0, d1);
    float euc  = sqrtf(d0 * d0 + d1 * d1);
    float h = (cheb + 0.001f * euc) + c_;
    bool st = startm[b * HW + i] > 0.5f;
    float flg = st ? 1.f : ((mapd[b * HW + i] > 0.5f) ? 0.f : 2.f);
    cell[i] = make_float4(0.f, flg, h, c_);
    pk[i] = make_float2(st ? expf(-((0.5f * h) * 0.125f)) : 0.f, c_);
  }
  __syncthreads();

  float gm = -1.f; int gidx = 0; float ggc = 0.f;
  {
    int base = lane << 6;
    for (int k = 0; k < 64; ++k) {
      int ci = base + ((k + lane) & 63);
      float2 p = pk[ci];
      if (p.x > gm || (p.x == gm && ci < gidx)) { gm = p.x; gidx = ci; ggc = p.y; }
    }
  }

  int t = 0;
  for (; t < 512; ++t) {
    float v = gm; int idx = gidx; float gc = ggc;
    #pragma unroll
    for (int m = 32; m; m >>= 1) {
      float vo = __shfl_xor(v, m);
      int   io = __shfl_xor(idx, m);
      float co = __shfl_xor(gc, m);
      bool take = (vo > v) || (vo == v && io < idx);
      if (take) { v = vo; idx = io; gc = co; }
    }
    const int ind = idx;
    const float g2 = gc;
    const bool unsolved = (ind != goal_idx);
    const int r = ind >> 6, cx = ind & 63;

    const int rb = (r << 6) + lane;
    float2 rp = pk[rb];

    int pcell = -1; float pval = 0.f, pgc = 0.f;
    if (lane < 8) {
      int kk = (lane >= 4) ? lane + 1 : lane;
      int ny = r + (kk / 3) - 1, nx = cx + (kk % 3) - 1;
      if ((unsigned)ny < 64u && (unsigned)nx < 64u) {
        int n = (ny << 6) + nx;
        float4 cd = cell[n];
        bool trig = (cd.y == 1.f) ? (cd.x > g2) : (cd.y == 0.f);
        if (trig) {
          float fv = expf(-((0.5f * g2 + 0.5f * cd.z) * 0.125f));
          *(float2*)&cell[n] = make_float2(g2, 1.f);
          pk[n] = make_float2(fv, g2 + cd.w);
          pcell = n; pval = fv; pgc = g2 + cd.w;
        }
      }
      Jcells[((size_t)b * 512 + t) * 8 + lane] =
          (unsigned short)(pcell >= 0 ? pcell : 0xFFFF);
    } else if (lane == 8) {
      if (unsolved) {
        cell[ind].y = 2.f;
        pk[ind].x  = 0.f;
      }
      Jmeta[b * 512 + t] = (unsigned short)(ind | (unsolved ? 0 : 0x8000));
    }

    float bv = (unsolved && lane == cx) ? -1.f : rp.x;
    int bi = rb; float bgc = rp.y;
    #pragma unroll
    for (int m = 32; m; m >>= 1) {
      float vo = __shfl_xor(bv, m);
      int   io = __shfl_xor(bi, m);
      float co = __shfl_xor(bgc, m);
      bool take = (vo > bv) || (vo == bv && io < bi);
      if (take) { bv = vo; bi = io; bgc = co; }
    }
    if (lane == r) { gm = bv; gidx = bi; ggc = bgc; }

    #pragma unroll
    for (int k = 0; k < 8; ++k) {
      int   pc = __shfl(pcell, k);
      float pv = __shfl(pval, k);
      float pg = __shfl(pgc, k);
      if (pc >= 0 && (pc >> 6) == lane) {
        if (pv > gm || (pv == gm && pc < gidx)) { gm = pv; gidx = pc; ggc = pg; }
      }
    }

    bool fixpoint = (!unsolved) && !__any(pcell >= 0);
    __syncthreads();
    if (fixpoint) { ++t; break; }
  }

  {
    unsigned short jm = (unsigned short)(goal_idx | 0x8000);
    uint4* jc4 = (uint4*)Jcells;
    for (int tt = t + lane; tt < 512; tt += 64) {
      Jmeta[b * 512 + tt] = jm;
      jc4[(size_t)b * 512 + tt] =
          make_uint4(0xFFFFFFFFu, 0xFFFFFFFFu, 0xFFFFFFFFu, 0xFFFFFFFFu);
    }
  }
}

// ---------------------------------------------------------------------------
// A* pass 2 (unchanged)
// ---------------------------------------------------------------------------
__global__ __launch_bounds__(64) void astar_pass2_kernel(
    const unsigned short* __restrict__ Jmeta,
    const unsigned short* __restrict__ Jcells,
    const float* __restrict__ goalm,
    float* __restrict__ out_hist, float* __restrict__ out_path)
{
  __shared__ unsigned short par[HW];
  __shared__ unsigned short jm[64];
  __shared__ unsigned short jc[64][8];
  const int b = blockIdx.x, lane = threadIdx.x;

  for (int i = lane; i < HW; i += 64) {
    out_hist[b * HW + i] = 0.f;
    out_path[b * HW + i] = 0.f;
  }
  int localmin = 512;
  for (int t = lane; t < 512; t += 64) {
    bool all16 = true;
    for (int bb = 0; bb < 16; ++bb)
      all16 = all16 && ((Jmeta[bb * 512 + t] & 0x8000u) != 0);
    if (all16) localmin = min(localmin, t);
  }
  #pragma unroll
  for (int m = 32; m; m >>= 1) localmin = min(localmin, __shfl_xor(localmin, m));
  const int t_last = (localmin < 512) ? localmin : 511;

  int gi = 0x7fffffff;
  for (int i = lane; i < HW; i += 64)
    if (goalm[b * HW + i] > 0.5f) gi = min(gi, i);
  #pragma unroll
  for (int m = 32; m; m >>= 1) gi = min(gi, __shfl_xor(gi, m));

  for (int i = lane; i < HW; i += 64) par[i] = (unsigned short)gi;
  __syncthreads();

  for (int t0 = 0; t0 <= t_last; t0 += 64) {
    if (t0 + lane < 512) {
      jm[lane] = Jmeta[b * 512 + t0 + lane];
      const unsigned short* src = &Jcells[((size_t)b * 512 + t0 + lane) * 8];
      #pragma unroll
      for (int k = 0; k < 8; ++k) jc[lane][k] = src[k];
    }
    __syncthreads();
    int te = min(t_last - t0, 63);
    for (int tt = 0; tt <= te; ++tt) {
      int ind = jm[tt] & 0x0FFF;
      if (lane < 8) {
        unsigned short c = jc[tt][lane];
        if (c != 0xFFFFu) par[c] = (unsigned short)ind;
      } else if (lane == 8) {
        out_hist[b * HW + ind] = 1.0f;
      }
    }
    __syncthreads();
  }
  if (lane == 0) {
    out_path[b * HW + gi] = 1.0f;
    int loc = par[gi];
    for (int i = 0; i < t_last; ++i) {
      out_path[b * HW + loc] = 1.0f;
      loc = par[loc];
    }
  }
}

// ---------------------------------------------------------------------------
extern "C" void kernel_launch(void* const* d_in, const int* in_sizes, int n_in,
                              void* d_out, int out_size, void* d_ws, size_t ws_size,
                              hipStream_t stream)
{
  (void)in_sizes; (void)n_in; (void)out_size;
  const float* mapd   = (const float*)d_in[0];
  const float* startm = (const float*)d_in[1];
  const float* goalm  = (const float*)d_in[2];
  const float* w0 = (const float*)d_in[3];
  const float* b0 = (const float*)d_in[4];
  const float* gm0= (const float*)d_in[5];
  const float* bt0= (const float*)d_in[6];
  const float* w1 = (const float*)d_in[7];
  const float* b1 = (const float*)d_in[8];
  const float* gm1= (const float*)d_in[9];
  const float* bt1= (const float*)d_in[10];
  const float* w2 = (const float*)d_in[11];
  const float* b2 = (const float*)d_in[12];
  const float* gm2= (const float*)d_in[13];
  const float* bt2= (const float*)d_in[14];
  const float* w3 = (const float*)d_in[15];
  const float* b3 = (const float*)d_in[16];
  const float* gm3= (const float*)d_in[17];
  const float* bt3= (const float*)d_in[18];
  const float* w4 = (const float*)d_in[19];
  const float* b4 = (const float*)d_in[20];
  const float* gm4= (const float*)d_in[21];
  const float* bt4= (const float*)d_in[22];
  const float* cw = (const float*)d_in[23];
  const float* cb = (const float*)d_in[24];
  const float* gw = (const float*)d_in[25];
  const float* gb = (const float*)d_in[26];
  const float* owp= (const float*)d_in[27];
  const float* obp= (const float*)d_in[28];
  float* out = (float*)d_out;

  float* wsf = (float*)d_ws;
  size_t off = 0;
  auto alloc = [&](size_t n) { float* p = wsf + off; off += n; return p; };
  float* wt0 = alloc(3 * 9 * 32);
  float* wt1 = alloc(32 * 9 * 64);
  float* wt2 = alloc(64 * 9 * 128);
  float* wt3 = alloc(128 * 9 * 256);
  float* in3   = alloc(16 * 3 * HW);
  float* costb = alloc(16 * HW);
  unsigned short* Jmeta  = (unsigned short*)alloc(16 * 512 / 2);
  unsigned short* Jcells = (unsigned short*)alloc(16 * 512 * 8 / 2);
  size_t fixed = off;

  // conv batch-group size: largest G whose ping-pong buffers fit the workspace
  int G = 16;
  while (G > 1 && (fixed + (size_t)G * 1572864ull) * sizeof(float) > ws_size) G >>= 1;
  float* bufA = alloc((size_t)G * 524288);    // up to 128 ch per batch
  float* bufB = alloc((size_t)G * 1048576);   // up to 256 ch per batch

  pack3_kernel<<<(16 * 3 * HW + 255) / 256, 256, 0, stream>>>(mapd, startm, goalm, in3);
  wtrans_kernel<<<(3 * 9 * 32 + 255) / 256, 256, 0, stream>>>(w0, wt0, 3, 32);
  wtrans_kernel<<<(32 * 9 * 64 + 255) / 256, 256, 0, stream>>>(w1, wt1, 32, 64);
  wtrans_kernel<<<(64 * 9 * 128 + 255) / 256, 256, 0, stream>>>(w2, wt2, 64, 128);
  wtrans_kernel<<<(128 * 9 * 256 + 255) / 256, 256, 0, stream>>>(w3, wt3, 128, 256);

  for (int g0 = 0; g0 < 16; g0 += G) {
    // L1: 3->32   CT=32, CO_T=16, NT=128
    conv3x3_kernel<3, 32, 3, 32, 16, true><<<dim3(16, 1, G), 128, 0, stream>>>(
        in3 + (size_t)g0 * 3 * HW, bufA, wt0, b0, gm0, bt0);
    // L2: 32->64  CT=64, CO_T=8, NT=512 (2048 waves -> 2/SIMD)
    conv3x3_kernel<32, 64, 8, 64, 8, true><<<dim3(16, 1, G), 512, 0, stream>>>(
        bufA, bufB, wt1, b1, gm1, bt1);
    // L3: 64->128 CT=64, CO_T=8, NT=512 (4096 waves -> 4/SIMD)
    conv3x3_kernel<64, 128, 8, 64, 8, true><<<dim3(16, 2, G), 512, 0, stream>>>(
        bufB, bufA, wt2, b2, gm2, bt2);
    // L4: 128->256 CT=64, CO_T=16, NT=256, CK=8 (4 blocks/CU, 16 waves/CU)
    conv3x3_kernel<128, 256, 8, 64, 16, true><<<dim3(16, 4, G), 256, 0, stream>>>(
        bufA, bufB, wt3, b3, gm3, bt3);
    conv_l4_heads_kernel<<<dim3(16, G), 256, 0, stream>>>(
        bufB, w4, b4, gm4, bt4, cw, cb, gw, gb, owp, obp,
        costb, out + 2 * 16 * HW, out + 3 * 16 * HW, g0);
  }

  astar_pass1_kernel<<<16, 64, 0, stream>>>(costb, startm, goalm, mapd, Jmeta, Jcells);
  astar_pass2_kernel<<<16, 64, 0, stream>>>(Jmeta, Jcells, goalm, out, out + 16 * HW);
}

// Round 5
// 894.645 us; speedup vs baseline: 2.2327x; 1.1043x over previous
//
#include <hip/hip_runtime.h>

#define HW 4096

typedef _Float16 f16;
typedef _Float16 f16x8 __attribute__((ext_vector_type(8)));
typedef float    f32x4 __attribute__((ext_vector_type(4)));

// ---------------------------------------------------------------------------
// pack [map, start, goal] -> [16][3][64][64]
// ---------------------------------------------------------------------------
__global__ __launch_bounds__(256) void pack3_kernel(
    const float* __restrict__ m, const float* __restrict__ s,
    const float* __restrict__ g, float* __restrict__ in3)
{
  int idx = blockIdx.x * 256 + threadIdx.x;
  if (idx >= 16 * 3 * HW) return;
  int p = idx & (HW - 1);
  int bc = idx >> 12;
  int c = bc % 3, b = bc / 3;
  const float* src = (c == 0) ? m : ((c == 1) ? s : g);
  in3[idx] = src[b * HW + p];
}

// ---------------------------------------------------------------------------
// weight transpose for L1: w[co][c][3][3] -> wt[(c*9+tap)][co]
// ---------------------------------------------------------------------------
__global__ __launch_bounds__(256) void wtrans_kernel(
    const float* __restrict__ w, float* __restrict__ wt, int cin, int cout)
{
  int idx = blockIdx.x * 256 + threadIdx.x;
  int total = cin * 9 * cout;
  if (idx >= total) return;
  int co = idx % cout;
  int rest = idx / cout;              // c*9+tap
  wt[idx] = w[co * cin * 9 + rest];
}

// ---------------------------------------------------------------------------
// weight split for MFMA layers: w[co][cin][3][3] f32 -> Whi/Wlo [co][9][cin]
// f16, with lo pre-scaled by 2^12 (keeps remainders normal f16; exact).
// ---------------------------------------------------------------------------
__global__ __launch_bounds__(256) void wsplit_kernel(
    const float* __restrict__ w, f16* __restrict__ wh, f16* __restrict__ wl,
    int cin, int cout)
{
  int idx = blockIdx.x * 256 + threadIdx.x;
  int total = cout * 9 * cin;
  if (idx >= total) return;
  int c = idx % cin;
  int rest = idx / cin;
  int tap = rest % 9, co = rest / 9;
  float v = w[((size_t)co * cin + c) * 9 + tap];
  f16 h = (f16)v;
  wh[idx] = h;
  wl[idx] = (f16)((v - (float)h) * 4096.0f);
}

// ---------------------------------------------------------------------------
// L1: direct f32 3->32 conv + BN + ReLU, output in padded NHWC f16 hi/lo
// ([66][66][32], zero halo maintained by upfront memset; interior writes only)
// ---------------------------------------------------------------------------
__global__ __launch_bounds__(128) void conv_l1_kernel(
    const float* __restrict__ in,    // [nb][3][64][64]
    f16* __restrict__ oh, f16* __restrict__ ol,   // [nb][66][66][32]
    const float* __restrict__ wt,    // [(c*9+tap)][32]
    const float* __restrict__ bconv,
    const float* __restrict__ gamma, const float* __restrict__ beta)
{
  __shared__ float sIn[3][18][20];
  __shared__ float sW[3][9][32];
  const int tile = blockIdx.x;
  const int b    = blockIdx.z;
  const int y0 = (tile >> 2) << 4, x0 = (tile & 3) << 4;
  const int tid = threadIdx.x;
  const int cg = tid >> 6;          // 0..1
  const int pg = tid & 63;
  const int py = pg >> 2, px0 = (pg & 3) << 2;

  float acc[4][16];
  #pragma unroll
  for (int i = 0; i < 4; ++i)
    #pragma unroll
    for (int j = 0; j < 16; ++j) acc[i][j] = 0.f;

  for (int idx = tid; idx < 3 * 324; idx += 128) {
    int c = idx / 324, rem = idx - c * 324;
    int iy = rem / 18, ix = rem - iy * 18;
    int gy = y0 - 1 + iy, gx = x0 - 1 + ix;
    float v = 0.f;
    if ((unsigned)gy < 64u && (unsigned)gx < 64u)
      v = in[(((size_t)b * 3 + c) << 12) + (gy << 6) + gx];
    sIn[c][iy][ix] = v;
  }
  for (int idx = tid; idx < 3 * 9 * 32; idx += 128) {
    int co = idx % 32;
    int rest = idx / 32;
    int tap = rest % 9, c = rest / 9;
    sW[c][tap][co] = wt[((size_t)c * 9 + tap) * 32 + co];
  }
  __syncthreads();
  for (int c = 0; c < 3; ++c) {
    #pragma unroll
    for (int dy = 0; dy < 3; ++dy) {
      const float* rowp = &sIn[c][py + dy][px0];
      float4 ra = *(const float4*)rowp;
      float4 rb = *(const float4*)(rowp + 4);
      float r[6] = {ra.x, ra.y, ra.z, ra.w, rb.x, rb.y};
      #pragma unroll
      for (int dx = 0; dx < 3; ++dx) {
        const float4* wp = (const float4*)&sW[c][dy * 3 + dx][cg * 16];
        float4 w0 = wp[0], w1 = wp[1], w2 = wp[2], w3 = wp[3];
        float wv[16] = {w0.x, w0.y, w0.z, w0.w, w1.x, w1.y, w1.z, w1.w,
                        w2.x, w2.y, w2.z, w2.w, w3.x, w3.y, w3.z, w3.w};
        #pragma unroll
        for (int i = 0; i < 4; ++i)
          #pragma unroll
          for (int j = 0; j < 16; ++j)
            acc[i][j] = fmaf(r[dx + i], wv[j], acc[i][j]);
      }
    }
  }
  #pragma unroll
  for (int j = 0; j < 16; ++j) {
    int co = cg * 16 + j;
    float sc = gamma[co] / sqrtf(1.0f + 1e-5f);
    float bb = bconv[co], sh = beta[co];
    #pragma unroll
    for (int i = 0; i < 4; ++i) {
      float v = (acc[i][j] + bb) * sc + sh;
      v = fmaxf(v, 0.f);
      size_t o = (((size_t)b * 66 + (y0 + py + 1)) * 66 + (x0 + px0 + i + 1)) * 32 + co;
      f16 h = (f16)v;
      oh[o] = h;
      ol[o] = (f16)((v - (float)h) * 4096.0f);
    }
  }
}

// ---------------------------------------------------------------------------
// MFMA implicit-GEMM 3x3 conv (f16x3 split, exact to ~2^-22 rel/product).
// In: padded NHWC hi/lo [nb][66][66][CIN].  Out: padded NHWC hi/lo (COUT) or
// f32 NCHW (F32OUT, for the heads consumer).
// Block: 16x16 spatial tile x 64 couts; 8 waves; wave w owns spatial rows
// {2w, 2w+1}; per mfma: M=16 couts, N=16 pixels (one row), K=32 cins @ 1 tap.
// Frag layouts (verified m89/m91): A/B lane&15=M/N idx, k=8*(lane>>4)+j;
// D: col(N)=lane&15, row(M)=4*(lane>>4)+reg.
// ---------------------------------------------------------------------------
template<int CIN, int COUT, bool F32OUT>
__global__ __launch_bounds__(512, 4) void mfmaconv_kernel(
    const f16* __restrict__ xh, const f16* __restrict__ xl,
    f16* __restrict__ oh, f16* __restrict__ ol,
    float* __restrict__ of32,
    const f16* __restrict__ wh, const f16* __restrict__ wl,   // [COUT][9][CIN]
    const float* __restrict__ bconv,
    const float* __restrict__ gamma, const float* __restrict__ beta)
{
  __shared__ __align__(16) f16 sH[324 * 32];
  __shared__ __align__(16) f16 sL[324 * 32];
  const int tid = threadIdx.x;
  const int w = tid >> 6, lane = tid & 63;
  const int l15 = lane & 15, lk = lane >> 4;
  const int y0 = (blockIdx.x >> 2) << 4, x0 = (blockIdx.x & 3) << 4;
  const int cog0 = blockIdx.y << 6;
  const int b = blockIdx.z;

  f32x4 acc1[4][2], acc2[4][2];
  #pragma unroll
  for (int mt = 0; mt < 4; ++mt)
    #pragma unroll
    for (int n2 = 0; n2 < 2; ++n2) { acc1[mt][n2] = (f32x4)0.f; acc2[mt][n2] = (f32x4)0.f; }

  for (int cc = 0; cc < CIN; cc += 32) {
    __syncthreads();
    for (int idx = tid; idx < 1296; idx += 512) {      // 324 halo px * 4 chunks
      int pix = idx >> 2, part = idx & 3;
      int hy = pix / 18, hx = pix - hy * 18;
      size_t goff = (((size_t)b * 66 + (y0 + hy)) * 66 + (x0 + hx)) * CIN + cc + part * 8;
      *(uint4*)&sH[idx * 8] = *(const uint4*)&xh[goff];
      *(uint4*)&sL[idx * 8] = *(const uint4*)&xl[goff];
    }
    __syncthreads();
    for (int tap = 0; tap < 9; ++tap) {
      const int dy = tap / 3, dx = tap - dy * 3;
      f16x8 Bh[2], Bl[2];
      #pragma unroll
      for (int n2 = 0; n2 < 2; ++n2) {
        int hp = (2 * w + n2 + dy) * 18 + (l15 + dx);
        Bh[n2] = *(const f16x8*)&sH[hp * 32 + 8 * lk];
        Bl[n2] = *(const f16x8*)&sL[hp * 32 + 8 * lk];
      }
      #pragma unroll
      for (int mt = 0; mt < 4; ++mt) {
        size_t woff = ((size_t)(cog0 + mt * 16 + l15) * 9 + tap) * CIN + cc + 8 * lk;
        f16x8 Ah = *(const f16x8*)&wh[woff];
        f16x8 Al = *(const f16x8*)&wl[woff];
        #pragma unroll
        for (int n2 = 0; n2 < 2; ++n2) {
          acc1[mt][n2] = __builtin_amdgcn_mfma_f32_16x16x32_f16(Ah, Bh[n2], acc1[mt][n2], 0, 0, 0);
          acc2[mt][n2] = __builtin_amdgcn_mfma_f32_16x16x32_f16(Ah, Bl[n2], acc2[mt][n2], 0, 0, 0);
          acc2[mt][n2] = __builtin_amdgcn_mfma_f32_16x16x32_f16(Al, Bh[n2], acc2[mt][n2], 0, 0, 0);
        }
      }
    }
  }

  #pragma unroll
  for (int mt = 0; mt < 4; ++mt)
    #pragma unroll
    for (int n2 = 0; n2 < 2; ++n2)
      #pragma unroll
      for (int i = 0; i < 4; ++i) {
        int co = cog0 + mt * 16 + 4 * lk + i;
        float v = acc1[mt][n2][i] + acc2[mt][n2][i] * (1.0f / 4096.0f);
        float sc = gamma[co] / sqrtf(1.0f + 1e-5f);
        v = (v + bconv[co]) * sc + beta[co];
        v = fmaxf(v, 0.f);
        int row = y0 + 2 * w + n2, col = x0 + l15;
        if constexpr (F32OUT) {
          of32[(((size_t)b * COUT + co) << 12) + (row << 6) + col] = v;
        } else {
          size_t o = (((size_t)b * 66 + (row + 1)) * 66 + (col + 1)) * COUT + co;
          f16 h = (f16)v;
          oh[o] = h;
          ol[o] = (f16)((v - (float)h) * 4096.0f);
        }
      }
}

// ---------------------------------------------------------------------------
// last conv (256->1) + BN (no relu) + the three 1x1 heads fused. (unchanged)
// ---------------------------------------------------------------------------
__global__ __launch_bounds__(256) void conv_l4_heads_kernel(
    const float* __restrict__ in,       // [nb][256][64][64]
    const float* __restrict__ w4,       // [256*9]
    const float* __restrict__ b4, const float* __restrict__ gm4,
    const float* __restrict__ bt4,
    const float* __restrict__ cw, const float* __restrict__ cb,
    const float* __restrict__ gw, const float* __restrict__ gb,
    const float* __restrict__ ow, const float* __restrict__ ob,
    float* __restrict__ costout,
    float* __restrict__ geoout, float* __restrict__ obsout,
    int b0)
{
  __shared__ float sIn[8][18][20];
  __shared__ float sW[8][9];
  const int tile = blockIdx.x, b = blockIdx.y;
  const int y0 = (tile >> 2) << 4, x0 = (tile & 3) << 4;
  const int tid = threadIdx.x;
  const int py = tid >> 4, px = tid & 15;
  float acc = 0.f;
  for (int cc = 0; cc < 256; cc += 8) {
    __syncthreads();
    for (int idx = tid; idx < 8 * 324; idx += 256) {
      int c = idx / 324, rem = idx - c * 324;
      int iy = rem / 18, ix = rem - iy * 18;
      int gy = y0 - 1 + iy, gx = x0 - 1 + ix;
      float v = 0.f;
      if ((unsigned)gy < 64u && (unsigned)gx < 64u)
        v = in[(((size_t)b * 256 + cc + c) << 12) + (gy << 6) + gx];
      sIn[c][iy][ix] = v;
    }
    if (tid < 72) sW[tid / 9][tid % 9] = w4[(cc + tid / 9) * 9 + tid % 9];
    __syncthreads();
    #pragma unroll
    for (int c = 0; c < 8; ++c)
      #pragma unroll
      for (int dy = 0; dy < 3; ++dy)
        #pragma unroll
        for (int dx = 0; dx < 3; ++dx)
          acc = fmaf(sIn[c][py + dy][px + dx], sW[c][dy * 3 + dx], acc);
  }
  float sc = gm4[0] / sqrtf(1.0f + 1e-5f);
  float f  = (acc + b4[0]) * sc + bt4[0];
  float cv = 1.f / (1.f + expf(-(f * cw[0] + cb[0])));
  float gv = fmaxf(f * gw[0] + gb[0], 0.f);
  float ov = fmaxf(f * ow[0] + ob[0], 0.f);
  int gbi = b0 + b;
  int pix = ((y0 + py) << 6) + (x0 + px);
  costout[gbi * HW + pix] = cv;
  geoout[gbi * HW + pix]  = gv;
  obsout[gbi * HW + pix]  = ov;
}

// ---------------------------------------------------------------------------
// A* pass 1 (unchanged -- proven correct & fast)
// ---------------------------------------------------------------------------
__global__ __launch_bounds__(64) void astar_pass1_kernel(
    const float* __restrict__ costm,
    const float* __restrict__ startm,
    const float* __restrict__ goalm,
    const float* __restrict__ mapd,
    unsigned short* __restrict__ Jmeta,
    unsigned short* __restrict__ Jcells)
{
  __shared__ float4 cell[HW];
  __shared__ float2 pk[HW];
  const int b = blockIdx.x, lane = threadIdx.x;

  int gi = 0x7fffffff;
  for (int i = lane; i < HW; i += 64)
    if (goalm[b * HW + i] > 0.5f) gi = min(gi, i);
  #pragma unroll
  for (int m = 32; m; m >>= 1) gi = min(gi, __shfl_xor(gi, m));
  const int goal_idx = gi;
  const float gyf = (float)(goal_idx >> 6), gxf = (float)(goal_idx & 63);

  for (int i = lane; i < HW; i += 64) {
    float c_ = costm[b * HW + i];
    float iy = (float)(i >> 6), ix = (float)(i & 63);
    float d0 = fabsf(iy - gyf), d1 = fabsf(ix - gxf);
    float cheb = (d0 + d1) - fminf(d0, d1);
    float euc  = sqrtf(d0 * d0 + d1 * d1);
    float h = (cheb + 0.001f * euc) + c_;
    bool st = startm[b * HW + i] > 0.5f;
    float flg = st ? 1.f : ((mapd[b * HW + i] > 0.5f) ? 0.f : 2.f);
    cell[i] = make_float4(0.f, flg, h, c_);
    pk[i] = make_float2(st ? expf(-((0.5f * h) * 0.125f)) : 0.f, c_);
  }
  __syncthreads();

  float gm = -1.f; int gidx = 0; float ggc = 0.f;
  {
    int base = lane << 6;
    for (int k = 0; k < 64; ++k) {
      int ci = base + ((k + lane) & 63);
      float2 p = pk[ci];
      if (p.x > gm || (p.x == gm && ci < gidx)) { gm = p.x; gidx = ci; ggc = p.y; }
    }
  }

  int t = 0;
  for (; t < 512; ++t) {
    float v = gm; int idx = gidx; float gc = ggc;
    #pragma unroll
    for (int m = 32; m; m >>= 1) {
      float vo = __shfl_xor(v, m);
      int   io = __shfl_xor(idx, m);
      float co = __shfl_xor(gc, m);
      bool take = (vo > v) || (vo == v && io < idx);
      if (take) { v = vo; idx = io; gc = co; }
    }
    const int ind = idx;
    const float g2 = gc;
    const bool unsolved = (ind != goal_idx);
    const int r = ind >> 6, cx = ind & 63;

    const int rb = (r << 6) + lane;
    float2 rp = pk[rb];

    int pcell = -1; float pval = 0.f, pgc = 0.f;
    if (lane < 8) {
      int kk = (lane >= 4) ? lane + 1 : lane;
      int ny = r + (kk / 3) - 1, nx = cx + (kk % 3) - 1;
      if ((unsigned)ny < 64u && (unsigned)nx < 64u) {
        int n = (ny << 6) + nx;
        float4 cd = cell[n];
        bool trig = (cd.y == 1.f) ? (cd.x > g2) : (cd.y == 0.f);
        if (trig) {
          float fv = expf(-((0.5f * g2 + 0.5f * cd.z) * 0.125f));
          *(float2*)&cell[n] = make_float2(g2, 1.f);
          pk[n] = make_float2(fv, g2 + cd.w);
          pcell = n; pval = fv; pgc = g2 + cd.w;
        }
      }
      Jcells[((size_t)b * 512 + t) * 8 + lane] =
          (unsigned short)(pcell >= 0 ? pcell : 0xFFFF);
    } else if (lane == 8) {
      if (unsolved) {
        cell[ind].y = 2.f;
        pk[ind].x  = 0.f;
      }
      Jmeta[b * 512 + t] = (unsigned short)(ind | (unsolved ? 0 : 0x8000));
    }

    float bv = (unsolved && lane == cx) ? -1.f : rp.x;
    int bi = rb; float bgc = rp.y;
    #pragma unroll
    for (int m = 32; m; m >>= 1) {
      float vo = __shfl_xor(bv, m);
      int   io = __shfl_xor(bi, m);
      float co = __shfl_xor(bgc, m);
      bool take = (vo > bv) || (vo == bv && io < bi);
      if (take) { bv = vo; bi = io; bgc = co; }
    }
    if (lane == r) { gm = bv; gidx = bi; ggc = bgc; }

    #pragma unroll
    for (int k = 0; k < 8; ++k) {
      int   pc = __shfl(pcell, k);
      float pv = __shfl(pval, k);
      float pg = __shfl(pgc, k);
      if (pc >= 0 && (pc >> 6) == lane) {
        if (pv > gm || (pv == gm && pc < gidx)) { gm = pv; gidx = pc; ggc = pg; }
      }
    }

    bool fixpoint = (!unsolved) && !__any(pcell >= 0);
    __syncthreads();
    if (fixpoint) { ++t; break; }
  }

  {
    unsigned short jm = (unsigned short)(goal_idx | 0x8000);
    uint4* jc4 = (uint4*)Jcells;
    for (int tt = t + lane; tt < 512; tt += 64) {
      Jmeta[b * 512 + tt] = jm;
      jc4[(size_t)b * 512 + tt] =
          make_uint4(0xFFFFFFFFu, 0xFFFFFFFFu, 0xFFFFFFFFu, 0xFFFFFFFFu);
    }
  }
}

// ---------------------------------------------------------------------------
// A* pass 2 (unchanged)
// ---------------------------------------------------------------------------
__global__ __launch_bounds__(64) void astar_pass2_kernel(
    const unsigned short* __restrict__ Jmeta,
    const unsigned short* __restrict__ Jcells,
    const float* __restrict__ goalm,
    float* __restrict__ out_hist, float* __restrict__ out_path)
{
  __shared__ unsigned short par[HW];
  __shared__ unsigned short jm[64];
  __shared__ unsigned short jc[64][8];
  const int b = blockIdx.x, lane = threadIdx.x;

  for (int i = lane; i < HW; i += 64) {
    out_hist[b * HW + i] = 0.f;
    out_path[b * HW + i] = 0.f;
  }
  int localmin = 512;
  for (int t = lane; t < 512; t += 64) {
    bool all16 = true;
    for (int bb = 0; bb < 16; ++bb)
      all16 = all16 && ((Jmeta[bb * 512 + t] & 0x8000u) != 0);
    if (all16) localmin = min(localmin, t);
  }
  #pragma unroll
  for (int m = 32; m; m >>= 1) localmin = min(localmin, __shfl_xor(localmin, m));
  const int t_last = (localmin < 512) ? localmin : 511;

  int gi = 0x7fffffff;
  for (int i = lane; i < HW; i += 64)
    if (goalm[b * HW + i] > 0.5f) gi = min(gi, i);
  #pragma unroll
  for (int m = 32; m; m >>= 1) gi = min(gi, __shfl_xor(gi, m));

  for (int i = lane; i < HW; i += 64) par[i] = (unsigned short)gi;
  __syncthreads();

  for (int t0 = 0; t0 <= t_last; t0 += 64) {
    if (t0 + lane < 512) {
      jm[lane] = Jmeta[b * 512 + t0 + lane];
      const unsigned short* src = &Jcells[((size_t)b * 512 + t0 + lane) * 8];
      #pragma unroll
      for (int k = 0; k < 8; ++k) jc[lane][k] = src[k];
    }
    __syncthreads();
    int te = min(t_last - t0, 63);
    for (int tt = 0; tt <= te; ++tt) {
      int ind = jm[tt] & 0x0FFF;
      if (lane < 8) {
        unsigned short c = jc[tt][lane];
        if (c != 0xFFFFu) par[c] = (unsigned short)ind;
      } else if (lane == 8) {
        out_hist[b * HW + ind] = 1.0f;
      }
    }
    __syncthreads();
  }
  if (lane == 0) {
    out_path[b * HW + gi] = 1.0f;
    int loc = par[gi];
    for (int i = 0; i < t_last; ++i) {
      out_path[b * HW + loc] = 1.0f;
      loc = par[loc];
    }
  }
}

// ---------------------------------------------------------------------------
extern "C" void kernel_launch(void* const* d_in, const int* in_sizes, int n_in,
                              void* d_out, int out_size, void* d_ws, size_t ws_size,
                              hipStream_t stream)
{
  (void)in_sizes; (void)n_in; (void)out_size;
  const float* mapd   = (const float*)d_in[0];
  const float* startm = (const float*)d_in[1];
  const float* goalm  = (const float*)d_in[2];
  const float* w0 = (const float*)d_in[3];
  const float* b0 = (const float*)d_in[4];
  const float* gm0= (const float*)d_in[5];
  const float* bt0= (const float*)d_in[6];
  const float* w1 = (const float*)d_in[7];
  const float* b1 = (const float*)d_in[8];
  const float* gm1= (const float*)d_in[9];
  const float* bt1= (const float*)d_in[10];
  const float* w2 = (const float*)d_in[11];
  const float* b2 = (const float*)d_in[12];
  const float* gm2= (const float*)d_in[13];
  const float* bt2= (const float*)d_in[14];
  const float* w3 = (const float*)d_in[15];
  const float* b3 = (const float*)d_in[16];
  const float* gm3= (const float*)d_in[17];
  const float* bt3= (const float*)d_in[18];
  const float* w4 = (const float*)d_in[19];
  const float* b4 = (const float*)d_in[20];
  const float* gm4= (const float*)d_in[21];
  const float* bt4= (const float*)d_in[22];
  const float* cw = (const float*)d_in[23];
  const float* cb = (const float*)d_in[24];
  const float* gw = (const float*)d_in[25];
  const float* gb = (const float*)d_in[26];
  const float* owp= (const float*)d_in[27];
  const float* obp= (const float*)d_in[28];
  float* out = (float*)d_out;

  char* wsb = (char*)d_ws;
  size_t off = 0;
  auto alloc = [&](size_t bytes) {
    void* p = wsb + off;
    off = (off + bytes + 255) & ~(size_t)255;
    return p;
  };
  float* wt0 = (float*)alloc(3 * 9 * 32 * 4);
  f16* wh1 = (f16*)alloc(64  * 9 * 32  * 2);
  f16* wl1 = (f16*)alloc(64  * 9 * 32  * 2);
  f16* wh2 = (f16*)alloc(128 * 9 * 64  * 2);
  f16* wl2 = (f16*)alloc(128 * 9 * 64  * 2);
  f16* wh3 = (f16*)alloc(256 * 9 * 128 * 2);
  f16* wl3 = (f16*)alloc(256 * 9 * 128 * 2);
  float* in3   = (float*)alloc(16 * 3 * HW * 4);
  float* costb = (float*)alloc(16 * HW * 4);
  unsigned short* Jmeta  = (unsigned short*)alloc(16 * 512 * 2);
  unsigned short* Jcells = (unsigned short*)alloc(16 * 512 * 8 * 2);
  size_t fixed = off;

  // per-batch activation buffer bytes (padded NHWC 66x66):
  const size_t A32  = 66 * 66 * 32  * 2;   // 278,784 B
  const size_t B64  = 66 * 66 * 64  * 2;   // 557,568 B
  const size_t A128 = 66 * 66 * 128 * 2;   // 1,115,136 B
  const size_t L4O  = 256 * HW * 4;        // 4,194,304 B
  const size_t perG = 2 * (A32 + B64 + A128) + L4O + 8 * 256;  // + align slack

  int G = 16;
  while (G > 1 && fixed + (size_t)G * perG > ws_size) G >>= 1;

  f16* a32h  = (f16*)alloc(G * A32);
  f16* a32l  = (f16*)alloc(G * A32);
  f16* b64h  = (f16*)alloc(G * B64);
  f16* b64l  = (f16*)alloc(G * B64);
  f16* a128h = (f16*)alloc(G * A128);
  f16* a128l = (f16*)alloc(G * A128);
  float* l4o = (float*)alloc(G * L4O);

  pack3_kernel<<<(16 * 3 * HW + 255) / 256, 256, 0, stream>>>(mapd, startm, goalm, in3);
  wtrans_kernel<<<(3 * 9 * 32 + 255) / 256, 256, 0, stream>>>(w0, wt0, 3, 32);
  wsplit_kernel<<<(64 * 9 * 32 + 255) / 256, 256, 0, stream>>>(w1, wh1, wl1, 32, 64);
  wsplit_kernel<<<(128 * 9 * 64 + 255) / 256, 256, 0, stream>>>(w2, wh2, wl2, 64, 128);
  wsplit_kernel<<<(256 * 9 * 128 + 255) / 256, 256, 0, stream>>>(w3, wh3, wl3, 128, 256);

  // zero halos (borders never written by epilogues; interiors rewritten)
  hipMemsetAsync(a32h,  0, G * A32,  stream);
  hipMemsetAsync(a32l,  0, G * A32,  stream);
  hipMemsetAsync(b64h,  0, G * B64,  stream);
  hipMemsetAsync(b64l,  0, G * B64,  stream);
  hipMemsetAsync(a128h, 0, G * A128, stream);
  hipMemsetAsync(a128l, 0, G * A128, stream);

  for (int g0 = 0; g0 < 16; g0 += G) {
    conv_l1_kernel<<<dim3(16, 1, G), 128, 0, stream>>>(
        in3 + (size_t)g0 * 3 * HW, a32h, a32l, wt0, b0, gm0, bt0);
    mfmaconv_kernel<32, 64, false><<<dim3(16, 1, G), 512, 0, stream>>>(
        a32h, a32l, b64h, b64l, nullptr, wh1, wl1, b1, gm1, bt1);
    mfmaconv_kernel<64, 128, false><<<dim3(16, 2, G), 512, 0, stream>>>(
        b64h, b64l, a128h, a128l, nullptr, wh2, wl2, b2, gm2, bt2);
    mfmaconv_kernel<128, 256, true><<<dim3(16, 4, G), 512, 0, stream>>>(
        a128h, a128l, nullptr, nullptr, l4o, wh3, wl3, b3, gm3, bt3);
    conv_l4_heads_kernel<<<dim3(16, G), 256, 0, stream>>>(
        l4o, w4, b4, gm4, bt4, cw, cb, gw, gb, owp, obp,
        costb, out + 2 * 16 * HW, out + 3 * 16 * HW, g0);
  }

  astar_pass1_kernel<<<16, 64, 0, stream>>>(costb, startm, goalm, mapd, Jmeta, Jcells);
  astar_pass2_kernel<<<16, 64, 0, stream>>>(Jmeta, Jcells, goalm, out, out + 16 * HW);
}

// Round 6
// 593.130 us; speedup vs baseline: 3.3677x; 1.5083x over previous
//
#include <hip/hip_runtime.h>

#define HW 4096

typedef _Float16 f16;
typedef _Float16 f16x4 __attribute__((ext_vector_type(4)));
typedef _Float16 f16x8 __attribute__((ext_vector_type(8)));
typedef float    f32x4 __attribute__((ext_vector_type(4)));

// ---------------------------------------------------------------------------
// pack [map, start, goal] -> [16][3][64][64]
// ---------------------------------------------------------------------------
__global__ __launch_bounds__(256) void pack3_kernel(
    const float* __restrict__ m, const float* __restrict__ s,
    const float* __restrict__ g, float* __restrict__ in3)
{
  int idx = blockIdx.x * 256 + threadIdx.x;
  if (idx >= 16 * 3 * HW) return;
  int p = idx & (HW - 1);
  int bc = idx >> 12;
  int c = bc % 3, b = bc / 3;
  const float* src = (c == 0) ? m : ((c == 1) ? s : g);
  in3[idx] = src[b * HW + p];
}

// ---------------------------------------------------------------------------
// weight transpose for L1: w[co][c][3][3] -> wt[(c*9+tap)][co]
// ---------------------------------------------------------------------------
__global__ __launch_bounds__(256) void wtrans_kernel(
    const float* __restrict__ w, float* __restrict__ wt, int cin, int cout)
{
  int idx = blockIdx.x * 256 + threadIdx.x;
  int total = cin * 9 * cout;
  if (idx >= total) return;
  int co = idx % cout;
  int rest = idx / cout;              // c*9+tap
  wt[idx] = w[co * cin * 9 + rest];
}

// ---------------------------------------------------------------------------
// weight repack for MFMA layers: w[co][cin][3][3] f32 ->
// wh/wl [cog][chunk][tap][mt][lane][8] f16 (A-fragment order, so one wave
// A-frag load = contiguous 1KB).  lo pre-scaled by 2^12 (exact split).
// idx bits: j(3) | lane(6) | mt(2) | (cog*chunks+chk)*9+tap
// ---------------------------------------------------------------------------
__global__ __launch_bounds__(256) void wrepack_kernel(
    const float* __restrict__ w, f16* __restrict__ wh, f16* __restrict__ wl,
    int cin, int cout)
{
  int idx = blockIdx.x * 256 + threadIdx.x;
  int total = cout * 9 * cin;
  if (idx >= total) return;
  int j    = idx & 7;
  int lane = (idx >> 3) & 63;
  int mt   = (idx >> 9) & 3;
  int t    = idx >> 11;
  int tap  = t % 9;
  int t2   = t / 9;
  int chunks = cin >> 5;
  int chk  = t2 % chunks;
  int cg   = t2 / chunks;
  int co = cg * 64 + mt * 16 + (lane & 15);
  int k  = chk * 32 + 8 * (lane >> 4) + j;
  float v = w[((size_t)co * cin + k) * 9 + tap];
  f16 h = (f16)v;
  wh[idx] = h;
  wl[idx] = (f16)((v - (float)h) * 4096.0f);
}

// ---------------------------------------------------------------------------
// L1: direct f32 3->32 conv + BN + ReLU -> padded NHWC f32 [66][66][32]
// (zero halo maintained by upfront memset; interior writes only)
// ---------------------------------------------------------------------------
__global__ __launch_bounds__(128) void conv_l1_kernel(
    const float* __restrict__ in,    // [nb][3][64][64]
    float* __restrict__ o32,         // [nb][66][66][32]
    const float* __restrict__ wt,    // [(c*9+tap)][32]
    const float* __restrict__ bconv,
    const float* __restrict__ gamma, const float* __restrict__ beta)
{
  __shared__ float sIn[3][18][20];
  __shared__ float sW[3][9][32];
  const int tile = blockIdx.x;
  const int b    = blockIdx.z;
  const int y0 = (tile >> 2) << 4, x0 = (tile & 3) << 4;
  const int tid = threadIdx.x;
  const int cg = tid >> 6;          // 0..1
  const int pg = tid & 63;
  const int py = pg >> 2, px0 = (pg & 3) << 2;

  float acc[4][16];
  #pragma unroll
  for (int i = 0; i < 4; ++i)
    #pragma unroll
    for (int j = 0; j < 16; ++j) acc[i][j] = 0.f;

  for (int idx = tid; idx < 3 * 324; idx += 128) {
    int c = idx / 324, rem = idx - c * 324;
    int iy = rem / 18, ix = rem - iy * 18;
    int gy = y0 - 1 + iy, gx = x0 - 1 + ix;
    float v = 0.f;
    if ((unsigned)gy < 64u && (unsigned)gx < 64u)
      v = in[(((size_t)b * 3 + c) << 12) + (gy << 6) + gx];
    sIn[c][iy][ix] = v;
  }
  for (int idx = tid; idx < 3 * 9 * 32; idx += 128) {
    int co = idx % 32;
    int rest = idx / 32;
    int tap = rest % 9, c = rest / 9;
    sW[c][tap][co] = wt[((size_t)c * 9 + tap) * 32 + co];
  }
  __syncthreads();
  for (int c = 0; c < 3; ++c) {
    #pragma unroll
    for (int dy = 0; dy < 3; ++dy) {
      const float* rowp = &sIn[c][py + dy][px0];
      float4 ra = *(const float4*)rowp;
      float4 rb = *(const float4*)(rowp + 4);
      float r[6] = {ra.x, ra.y, ra.z, ra.w, rb.x, rb.y};
      #pragma unroll
      for (int dx = 0; dx < 3; ++dx) {
        const float4* wp = (const float4*)&sW[c][dy * 3 + dx][cg * 16];
        float4 w0 = wp[0], w1 = wp[1], w2 = wp[2], w3 = wp[3];
        float wv[16] = {w0.x, w0.y, w0.z, w0.w, w1.x, w1.y, w1.z, w1.w,
                        w2.x, w2.y, w2.z, w2.w, w3.x, w3.y, w3.z, w3.w};
        #pragma unroll
        for (int i = 0; i < 4; ++i)
          #pragma unroll
          for (int j = 0; j < 16; ++j)
            acc[i][j] = fmaf(r[dx + i], wv[j], acc[i][j]);
      }
    }
  }
  #pragma unroll
  for (int j = 0; j < 16; ++j) {
    int co = cg * 16 + j;
    float sc = gamma[co] / sqrtf(1.0f + 1e-5f);
    float bb = bconv[co], sh = beta[co];
    #pragma unroll
    for (int i = 0; i < 4; ++i) {
      float v = (acc[i][j] + bb) * sc + sh;
      v = fmaxf(v, 0.f);
      o32[(((size_t)b * 66 + (y0 + py + 1)) * 66 + (x0 + px0 + i + 1)) * 32 + co] = v;
    }
  }
}

// ---------------------------------------------------------------------------
// MFMA implicit-GEMM 3x3 conv, f16x3 split (exact to ~2^-22 rel/product).
// In: padded NHWC f32 [nb][66][66][CIN] (zero halo).
// Out: padded NHWC f32 (COUT) or plain NCHW f32 (F32OUT).
// Block: 4 rows x 64 cols x 64 couts; 8 waves: wave w -> row rw=w&3,
// col-half ch2=w>>2 (two 16-px n-tiles each).  Weights pre-repacked in
// A-frag order -> coalesced, L1-shared loads.  Split hi/lo computed during
// LDS staging.  Epilogue: 2x 32-cout passes through LDS [256][33] f32
// transpose -> fully coalesced float4 global stores.
// Frag maps (verified m89/m91): A/B lane&15 = M/N idx, k=8*(lane>>4)+j;
// D: col(N)=lane&15, row(M)=4*(lane>>4)+reg.
// ---------------------------------------------------------------------------
template<int CIN, int COUT, bool F32OUT>
__global__ __launch_bounds__(512, 4) void mfmaconv_kernel(
    const float* __restrict__ x,
    float* __restrict__ onhwc,
    float* __restrict__ of32,
    const f16* __restrict__ wh, const f16* __restrict__ wl,
    const float* __restrict__ bconv,
    const float* __restrict__ gamma, const float* __restrict__ beta)
{
  constexpr int CHUNKS = CIN / 32;
  __shared__ __align__(16) char smem[396 * 32 * 2 * 2];   // 50688 B
  f16* sH = (f16*)smem;
  f16* sL = sH + 396 * 32;
  float (*sT)[33] = (float(*)[33])smem;                    // 33792 B, reused

  const int tid  = threadIdx.x;
  const int w    = tid >> 6, lane = tid & 63;
  const int l15  = lane & 15, lk = lane >> 4;
  const int rw   = w & 3, ch2 = w >> 2;
  const int tile = blockIdx.x;           // 0..15 (4 rows each)
  const int y0g  = tile << 2;
  const int cog  = blockIdx.y;
  const int cog0 = cog << 6;
  const int b    = blockIdx.z;

  f32x4 acc1[4][2], acc2[4][2];
  #pragma unroll
  for (int mt = 0; mt < 4; ++mt)
    #pragma unroll
    for (int n2 = 0; n2 < 2; ++n2) { acc1[mt][n2] = (f32x4)0.f; acc2[mt][n2] = (f32x4)0.f; }

  for (int chk = 0; chk < CHUNKS; ++chk) {
    __syncthreads();
    // stage halo (6 rows x 66 cols x 32 ch) as f16 hi/lo split
    for (int idx = tid; idx < 3168; idx += 512) {
      int px = idx >> 3, c4 = idx & 7;
      int r = px / 66, c = px - r * 66;
      float4 v = *(const float4*)&x[(((size_t)b * 66 + y0g + r) * 66 + c) * CIN
                                    + chk * 32 + c4 * 4];
      float vv[4] = {v.x, v.y, v.z, v.w};
      f16x4 hv, lv;
      #pragma unroll
      for (int j = 0; j < 4; ++j) {
        f16 h = (f16)vv[j];
        hv[j] = h;
        lv[j] = (f16)((vv[j] - (float)h) * 4096.0f);
      }
      *(f16x4*)&sH[px * 32 + c4 * 4] = hv;
      *(f16x4*)&sL[px * 32 + c4 * 4] = lv;
    }
    __syncthreads();
    #pragma unroll
    for (int tap = 0; tap < 9; ++tap) {
      const int dy = tap / 3, dx = tap - dy * 3;
      f16x8 Bh[2], Bl[2];
      #pragma unroll
      for (int n2 = 0; n2 < 2; ++n2) {
        int hp = (rw + dy) * 66 + (ch2 * 32 + n2 * 16 + l15 + dx);
        Bh[n2] = *(const f16x8*)&sH[hp * 32 + 8 * lk];
        Bl[n2] = *(const f16x8*)&sL[hp * 32 + 8 * lk];
      }
      #pragma unroll
      for (int mt = 0; mt < 4; ++mt) {
        size_t aoff = ((((size_t)(cog * CHUNKS + chk) * 9 + tap) * 4 + mt) * 64 + lane) * 8;
        f16x8 Ah = *(const f16x8*)&wh[aoff];
        f16x8 Al = *(const f16x8*)&wl[aoff];
        #pragma unroll
        for (int n2 = 0; n2 < 2; ++n2) {
          acc1[mt][n2] = __builtin_amdgcn_mfma_f32_16x16x32_f16(Ah, Bh[n2], acc1[mt][n2], 0, 0, 0);
          acc2[mt][n2] = __builtin_amdgcn_mfma_f32_16x16x32_f16(Ah, Bl[n2], acc2[mt][n2], 0, 0, 0);
          acc2[mt][n2] = __builtin_amdgcn_mfma_f32_16x16x32_f16(Al, Bh[n2], acc2[mt][n2], 0, 0, 0);
        }
      }
    }
  }

  // epilogue: two 32-cout passes via LDS transpose
  #pragma unroll
  for (int p = 0; p < 2; ++p) {
    __syncthreads();
    #pragma unroll
    for (int m1 = 0; m1 < 2; ++m1) {
      const int mt = 2 * p + m1;
      #pragma unroll
      for (int n2 = 0; n2 < 2; ++n2)
        #pragma unroll
        for (int i = 0; i < 4; ++i) {
          int co = cog0 + p * 32 + m1 * 16 + 4 * lk + i;
          float v = acc1[mt][n2][i] + acc2[mt][n2][i] * (1.0f / 4096.0f);
          float sc = gamma[co] / sqrtf(1.0f + 1e-5f);
          v = (v + bconv[co]) * sc + beta[co];
          v = fmaxf(v, 0.f);
          sT[rw * 64 + ch2 * 32 + n2 * 16 + l15][m1 * 16 + 4 * lk + i] = v;
        }
    }
    __syncthreads();
    if constexpr (F32OUT) {
      int co32 = tid >> 4, pxg = tid & 15;
      size_t base = (((size_t)b * COUT + cog0 + p * 32 + co32) << 12) + tile * 256 + pxg * 16;
      #pragma unroll
      for (int jj = 0; jj < 4; ++jj) {
        float4 o;
        o.x = sT[pxg * 16 + jj * 4 + 0][co32];
        o.y = sT[pxg * 16 + jj * 4 + 1][co32];
        o.z = sT[pxg * 16 + jj * 4 + 2][co32];
        o.w = sT[pxg * 16 + jj * 4 + 3][co32];
        *(float4*)&of32[base + jj * 4] = o;
      }
    } else {
      int px = tid >> 1, half = tid & 1;
      int row = px >> 6, col = px & 63;
      size_t base = (((size_t)b * 66 + y0g + row + 1) * 66 + col + 1) * COUT
                    + cog0 + p * 32 + half * 16;
      #pragma unroll
      for (int jj = 0; jj < 4; ++jj) {
        float4 o;
        o.x = sT[px][half * 16 + jj * 4 + 0];
        o.y = sT[px][half * 16 + jj * 4 + 1];
        o.z = sT[px][half * 16 + jj * 4 + 2];
        o.w = sT[px][half * 16 + jj * 4 + 3];
        *(float4*)&onhwc[base + jj * 4] = o;
      }
    }
  }
}

// ---------------------------------------------------------------------------
// last conv (256->1) + BN (no relu) + the three 1x1 heads fused.
// ---------------------------------------------------------------------------
__global__ __launch_bounds__(256) void conv_l4_heads_kernel(
    const float* __restrict__ in,       // [nb][256][64][64]
    const float* __restrict__ w4,       // [256*9]
    const float* __restrict__ b4, const float* __restrict__ gm4,
    const float* __restrict__ bt4,
    const float* __restrict__ cw, const float* __restrict__ cb,
    const float* __restrict__ gw, const float* __restrict__ gb,
    const float* __restrict__ ow, const float* __restrict__ ob,
    float* __restrict__ costout,
    float* __restrict__ geoout, float* __restrict__ obsout,
    int b0)
{
  __shared__ float sIn[8][18][20];
  __shared__ float sW[8][9];
  const int tile = blockIdx.x, b = blockIdx.y;
  const int y0 = (tile >> 2) << 4, x0 = (tile & 3) << 4;
  const int tid = threadIdx.x;
  const int py = tid >> 4, px = tid & 15;
  float acc = 0.f;
  for (int cc = 0; cc < 256; cc += 8) {
    __syncthreads();
    for (int idx = tid; idx < 8 * 324; idx += 256) {
      int c = idx / 324, rem = idx - c * 324;
      int iy = rem / 18, ix = rem - iy * 18;
      int gy = y0 - 1 + iy, gx = x0 - 1 + ix;
      float v = 0.f;
      if ((unsigned)gy < 64u && (unsigned)gx < 64u)
        v = in[(((size_t)b * 256 + cc + c) << 12) + (gy << 6) + gx];
      sIn[c][iy][ix] = v;
    }
    if (tid < 72) sW[tid / 9][tid % 9] = w4[(cc + tid / 9) * 9 + tid % 9];
    __syncthreads();
    #pragma unroll
    for (int c = 0; c < 8; ++c)
      #pragma unroll
      for (int dy = 0; dy < 3; ++dy)
        #pragma unroll
        for (int dx = 0; dx < 3; ++dx)
          acc = fmaf(sIn[c][py + dy][px + dx], sW[c][dy * 3 + dx], acc);
  }
  float sc = gm4[0] / sqrtf(1.0f + 1e-5f);
  float f  = (acc + b4[0]) * sc + bt4[0];
  float cv = 1.f / (1.f + expf(-(f * cw[0] + cb[0])));
  float gv = fmaxf(f * gw[0] + gb[0], 0.f);
  float ov = fmaxf(f * ow[0] + ob[0], 0.f);
  int gbi = b0 + b;
  int pix = ((y0 + py) << 6) + (x0 + px);
  costout[gbi * HW + pix] = cv;
  geoout[gbi * HW + pix]  = gv;
  obsout[gbi * HW + pix]  = ov;
}

// ---------------------------------------------------------------------------
// A* pass 1 (unchanged -- proven correct & fast)
// ---------------------------------------------------------------------------
__global__ __launch_bounds__(64) void astar_pass1_kernel(
    const float* __restrict__ costm,
    const float* __restrict__ startm,
    const float* __restrict__ goalm,
    const float* __restrict__ mapd,
    unsigned short* __restrict__ Jmeta,
    unsigned short* __restrict__ Jcells)
{
  __shared__ float4 cell[HW];
  __shared__ float2 pk[HW];
  const int b = blockIdx.x, lane = threadIdx.x;

  int gi = 0x7fffffff;
  for (int i = lane; i < HW; i += 64)
    if (goalm[b * HW + i] > 0.5f) gi = min(gi, i);
  #pragma unroll
  for (int m = 32; m; m >>= 1) gi = min(gi, __shfl_xor(gi, m));
  const int goal_idx = gi;
  const float gyf = (float)(goal_idx >> 6), gxf = (float)(goal_idx & 63);

  for (int i = lane; i < HW; i += 64) {
    float c_ = costm[b * HW + i];
    float iy = (float)(i >> 6), ix = (float)(i & 63);
    float d0 = fabsf(iy - gyf), d1 = fabsf(ix - gxf);
    float cheb = (d0 + d1) - fminf(d0, d1);
    float euc  = sqrtf(d0 * d0 + d1 * d1);
    float h = (cheb + 0.001f * euc) + c_;
    bool st = startm[b * HW + i] > 0.5f;
    float flg = st ? 1.f : ((mapd[b * HW + i] > 0.5f) ? 0.f : 2.f);
    cell[i] = make_float4(0.f, flg, h, c_);
    pk[i] = make_float2(st ? expf(-((0.5f * h) * 0.125f)) : 0.f, c_);
  }
  __syncthreads();

  float gm = -1.f; int gidx = 0; float ggc = 0.f;
  {
    int base = lane << 6;
    for (int k = 0; k < 64; ++k) {
      int ci = base + ((k + lane) & 63);
      float2 p = pk[ci];
      if (p.x > gm || (p.x == gm && ci < gidx)) { gm = p.x; gidx = ci; ggc = p.y; }
    }
  }

  int t = 0;
  for (; t < 512; ++t) {
    float v = gm; int idx = gidx; float gc = ggc;
    #pragma unroll
    for (int m = 32; m; m >>= 1) {
      float vo = __shfl_xor(v, m);
      int   io = __shfl_xor(idx, m);
      float co = __shfl_xor(gc, m);
      bool take = (vo > v) || (vo == v && io < idx);
      if (take) { v = vo; idx = io; gc = co; }
    }
    const int ind = idx;
    const float g2 = gc;
    const bool unsolved = (ind != goal_idx);
    const int r = ind >> 6, cx = ind & 63;

    const int rb = (r << 6) + lane;
    float2 rp = pk[rb];

    int pcell = -1; float pval = 0.f, pgc = 0.f;
    if (lane < 8) {
      int kk = (lane >= 4) ? lane + 1 : lane;
      int ny = r + (kk / 3) - 1, nx = cx + (kk % 3) - 1;
      if ((unsigned)ny < 64u && (unsigned)nx < 64u) {
        int n = (ny << 6) + nx;
        float4 cd = cell[n];
        bool trig = (cd.y == 1.f) ? (cd.x > g2) : (cd.y == 0.f);
        if (trig) {
          float fv = expf(-((0.5f * g2 + 0.5f * cd.z) * 0.125f));
          *(float2*)&cell[n] = make_float2(g2, 1.f);
          pk[n] = make_float2(fv, g2 + cd.w);
          pcell = n; pval = fv; pgc = g2 + cd.w;
        }
      }
      Jcells[((size_t)b * 512 + t) * 8 + lane] =
          (unsigned short)(pcell >= 0 ? pcell : 0xFFFF);
    } else if (lane == 8) {
      if (unsolved) {
        cell[ind].y = 2.f;
        pk[ind].x  = 0.f;
      }
      Jmeta[b * 512 + t] = (unsigned short)(ind | (unsolved ? 0 : 0x8000));
    }

    float bv = (unsolved && lane == cx) ? -1.f : rp.x;
    int bi = rb; float bgc = rp.y;
    #pragma unroll
    for (int m = 32; m; m >>= 1) {
      float vo = __shfl_xor(bv, m);
      int   io = __shfl_xor(bi, m);
      float co = __shfl_xor(bgc, m);
      bool take = (vo > bv) || (vo == bv && io < bi);
      if (take) { bv = vo; bi = io; bgc = co; }
    }
    if (lane == r) { gm = bv; gidx = bi; ggc = bgc; }

    #pragma unroll
    for (int k = 0; k < 8; ++k) {
      int   pc = __shfl(pcell, k);
      float pv = __shfl(pval, k);
      float pg = __shfl(pgc, k);
      if (pc >= 0 && (pc >> 6) == lane) {
        if (pv > gm || (pv == gm && pc < gidx)) { gm = pv; gidx = pc; ggc = pg; }
      }
    }

    bool fixpoint = (!unsolved) && !__any(pcell >= 0);
    __syncthreads();
    if (fixpoint) { ++t; break; }
  }

  {
    unsigned short jm = (unsigned short)(goal_idx | 0x8000);
    uint4* jc4 = (uint4*)Jcells;
    for (int tt = t + lane; tt < 512; tt += 64) {
      Jmeta[b * 512 + tt] = jm;
      jc4[(size_t)b * 512 + tt] =
          make_uint4(0xFFFFFFFFu, 0xFFFFFFFFu, 0xFFFFFFFFu, 0xFFFFFFFFu);
    }
  }
}

// ---------------------------------------------------------------------------
// A* pass 2 (unchanged)
// ---------------------------------------------------------------------------
__global__ __launch_bounds__(64) void astar_pass2_kernel(
    const unsigned short* __restrict__ Jmeta,
    const unsigned short* __restrict__ Jcells,
    const float* __restrict__ goalm,
    float* __restrict__ out_hist, float* __restrict__ out_path)
{
  __shared__ unsigned short par[HW];
  __shared__ unsigned short jm[64];
  __shared__ unsigned short jc[64][8];
  const int b = blockIdx.x, lane = threadIdx.x;

  for (int i = lane; i < HW; i += 64) {
    out_hist[b * HW + i] = 0.f;
    out_path[b * HW + i] = 0.f;
  }
  int localmin = 512;
  for (int t = lane; t < 512; t += 64) {
    bool all16 = true;
    for (int bb = 0; bb < 16; ++bb)
      all16 = all16 && ((Jmeta[bb * 512 + t] & 0x8000u) != 0);
    if (all16) localmin = min(localmin, t);
  }
  #pragma unroll
  for (int m = 32; m; m >>= 1) localmin = min(localmin, __shfl_xor(localmin, m));
  const int t_last = (localmin < 512) ? localmin : 511;

  int gi = 0x7fffffff;
  for (int i = lane; i < HW; i += 64)
    if (goalm[b * HW + i] > 0.5f) gi = min(gi, i);
  #pragma unroll
  for (int m = 32; m; m >>= 1) gi = min(gi, __shfl_xor(gi, m));

  for (int i = lane; i < HW; i += 64) par[i] = (unsigned short)gi;
  __syncthreads();

  for (int t0 = 0; t0 <= t_last; t0 += 64) {
    if (t0 + lane < 512) {
      jm[lane] = Jmeta[b * 512 + t0 + lane];
      const unsigned short* src = &Jcells[((size_t)b * 512 + t0 + lane) * 8];
      #pragma unroll
      for (int k = 0; k < 8; ++k) jc[lane][k] = src[k];
    }
    __syncthreads();
    int te = min(t_last - t0, 63);
    for (int tt = 0; tt <= te; ++tt) {
      int ind = jm[tt] & 0x0FFF;
      if (lane < 8) {
        unsigned short c = jc[tt][lane];
        if (c != 0xFFFFu) par[c] = (unsigned short)ind;
      } else if (lane == 8) {
        out_hist[b * HW + ind] = 1.0f;
      }
    }
    __syncthreads();
  }
  if (lane == 0) {
    out_path[b * HW + gi] = 1.0f;
    int loc = par[gi];
    for (int i = 0; i < t_last; ++i) {
      out_path[b * HW + loc] = 1.0f;
      loc = par[loc];
    }
  }
}

// ---------------------------------------------------------------------------
extern "C" void kernel_launch(void* const* d_in, const int* in_sizes, int n_in,
                              void* d_out, int out_size, void* d_ws, size_t ws_size,
                              hipStream_t stream)
{
  (void)in_sizes; (void)n_in; (void)out_size;
  const float* mapd   = (const float*)d_in[0];
  const float* startm = (const float*)d_in[1];
  const float* goalm  = (const float*)d_in[2];
  const float* w0 = (const float*)d_in[3];
  const float* b0 = (const float*)d_in[4];
  const float* gm0= (const float*)d_in[5];
  const float* bt0= (const float*)d_in[6];
  const float* w1 = (const float*)d_in[7];
  const float* b1 = (const float*)d_in[8];
  const float* gm1= (const float*)d_in[9];
  const float* bt1= (const float*)d_in[10];
  const float* w2 = (const float*)d_in[11];
  const float* b2 = (const float*)d_in[12];
  const float* gm2= (const float*)d_in[13];
  const float* bt2= (const float*)d_in[14];
  const float* w3 = (const float*)d_in[15];
  const float* b3 = (const float*)d_in[16];
  const float* gm3= (const float*)d_in[17];
  const float* bt3= (const float*)d_in[18];
  const float* w4 = (const float*)d_in[19];
  const float* b4 = (const float*)d_in[20];
  const float* gm4= (const float*)d_in[21];
  const float* bt4= (const float*)d_in[22];
  const float* cw = (const float*)d_in[23];
  const float* cb = (const float*)d_in[24];
  const float* gw = (const float*)d_in[25];
  const float* gb = (const float*)d_in[26];
  const float* owp= (const float*)d_in[27];
  const float* obp= (const float*)d_in[28];
  float* out = (float*)d_out;

  char* wsb = (char*)d_ws;
  size_t off = 0;
  auto alloc = [&](size_t bytes) {
    void* p = wsb + off;
    off = (off + bytes + 255) & ~(size_t)255;
    return p;
  };
  float* wt0 = (float*)alloc(3 * 9 * 32 * 4);
  f16* wh1 = (f16*)alloc(64  * 9 * 32  * 2);
  f16* wl1 = (f16*)alloc(64  * 9 * 32  * 2);
  f16* wh2 = (f16*)alloc(128 * 9 * 64  * 2);
  f16* wl2 = (f16*)alloc(128 * 9 * 64  * 2);
  f16* wh3 = (f16*)alloc(256 * 9 * 128 * 2);
  f16* wl3 = (f16*)alloc(256 * 9 * 128 * 2);
  float* in3   = (float*)alloc(16 * 3 * HW * 4);
  float* costb = (float*)alloc(16 * HW * 4);
  unsigned short* Jmeta  = (unsigned short*)alloc(16 * 512 * 2);
  unsigned short* Jcells = (unsigned short*)alloc(16 * 512 * 8 * 2);
  size_t fixed = off;

  // per-batch activation bytes (padded NHWC f32 66x66)
  const size_t A32  = 66 * 66 * 32  * 4;   // 557,568
  const size_t B64  = 66 * 66 * 64  * 4;   // 1,115,136
  const size_t A128 = 66 * 66 * 128 * 4;   // 2,230,272
  const size_t L4O  = 256 * HW * 4;        // 4,194,304
  const size_t perG = A32 + B64 + A128 + L4O + 4 * 256;

  int G = 16;
  while (G > 1 && fixed + (size_t)G * perG > ws_size) G >>= 1;

  float* a32f  = (float*)alloc(G * A32);
  float* b64f  = (float*)alloc(G * B64);
  float* a128f = (float*)alloc(G * A128);
  float* l4o   = (float*)alloc(G * L4O);

  pack3_kernel<<<(16 * 3 * HW + 255) / 256, 256, 0, stream>>>(mapd, startm, goalm, in3);
  wtrans_kernel<<<(3 * 9 * 32 + 255) / 256, 256, 0, stream>>>(w0, wt0, 3, 32);
  wrepack_kernel<<<(64 * 9 * 32 + 255) / 256, 256, 0, stream>>>(w1, wh1, wl1, 32, 64);
  wrepack_kernel<<<(128 * 9 * 64 + 255) / 256, 256, 0, stream>>>(w2, wh2, wl2, 64, 128);
  wrepack_kernel<<<(256 * 9 * 128 + 255) / 256, 256, 0, stream>>>(w3, wh3, wl3, 128, 256);

  // zero halos (borders never written by epilogues; interiors rewritten)
  hipMemsetAsync(a32f,  0, G * A32,  stream);
  hipMemsetAsync(b64f,  0, G * B64,  stream);
  hipMemsetAsync(a128f, 0, G * A128, stream);

  for (int g0 = 0; g0 < 16; g0 += G) {
    conv_l1_kernel<<<dim3(16, 1, G), 128, 0, stream>>>(
        in3 + (size_t)g0 * 3 * HW, a32f, wt0, b0, gm0, bt0);
    mfmaconv_kernel<32, 64, false><<<dim3(16, 1, G), 512, 0, stream>>>(
        a32f, b64f, nullptr, wh1, wl1, b1, gm1, bt1);
    mfmaconv_kernel<64, 128, false><<<dim3(16, 2, G), 512, 0, stream>>>(
        b64f, a128f, nullptr, wh2, wl2, b2, gm2, bt2);
    mfmaconv_kernel<128, 256, true><<<dim3(16, 4, G), 512, 0, stream>>>(
        a128f, nullptr, l4o, wh3, wl3, b3, gm3, bt3);
    conv_l4_heads_kernel<<<dim3(16, G), 256, 0, stream>>>(
        l4o, w4, b4, gm4, bt4, cw, cb, gw, gb, owp, obp,
        costb, out + 2 * 16 * HW, out + 3 * 16 * HW, g0);
  }

  astar_pass1_kernel<<<16, 64, 0, stream>>>(costb, startm, goalm, mapd, Jmeta, Jcells);
  astar_pass2_kernel<<<16, 64, 0, stream>>>(Jmeta, Jcells, goalm, out, out + 16 * HW);
}

// Round 7
// 592.227 us; speedup vs baseline: 3.3728x; 1.0015x over previous
//
#include <hip/hip_runtime.h>

#define HW 4096

typedef _Float16 f16;
typedef _Float16 f16x4 __attribute__((ext_vector_type(4)));
typedef _Float16 f16x8 __attribute__((ext_vector_type(8)));
typedef float    f32x4 __attribute__((ext_vector_type(4)));

// ---------------------------------------------------------------------------
// pack [map, start, goal] -> [16][3][64][64]
// ---------------------------------------------------------------------------
__global__ __launch_bounds__(256) void pack3_kernel(
    const float* __restrict__ m, const float* __restrict__ s,
    const float* __restrict__ g, float* __restrict__ in3)
{
  int idx = blockIdx.x * 256 + threadIdx.x;
  if (idx >= 16 * 3 * HW) return;
  int p = idx & (HW - 1);
  int bc = idx >> 12;
  int c = bc % 3, b = bc / 3;
  const float* src = (c == 0) ? m : ((c == 1) ? s : g);
  in3[idx] = src[b * HW + p];
}

// ---------------------------------------------------------------------------
// weight transpose for L1: w[co][c][3][3] -> wt[(c*9+tap)][co]
// ---------------------------------------------------------------------------
__global__ __launch_bounds__(256) void wtrans_kernel(
    const float* __restrict__ w, float* __restrict__ wt, int cin, int cout)
{
  int idx = blockIdx.x * 256 + threadIdx.x;
  int total = cin * 9 * cout;
  if (idx >= total) return;
  int co = idx % cout;
  int rest = idx / cout;              // c*9+tap
  wt[idx] = w[co * cin * 9 + rest];
}

// ---------------------------------------------------------------------------
// weight repack for MFMA layers: w[co][cin][3][3] f32 ->
// wh/wl [cog][chunk][tap][mt][lane][8] f16 (A-fragment order, so one wave
// A-frag load = contiguous 1KB).  lo pre-scaled by 2^12 (exact split).
// ---------------------------------------------------------------------------
__global__ __launch_bounds__(256) void wrepack_kernel(
    const float* __restrict__ w, f16* __restrict__ wh, f16* __restrict__ wl,
    int cin, int cout)
{
  int idx = blockIdx.x * 256 + threadIdx.x;
  int total = cout * 9 * cin;
  if (idx >= total) return;
  int j    = idx & 7;
  int lane = (idx >> 3) & 63;
  int mt   = (idx >> 9) & 3;
  int t    = idx >> 11;
  int tap  = t % 9;
  int t2   = t / 9;
  int chunks = cin >> 5;
  int chk  = t2 % chunks;
  int cg   = t2 / chunks;
  int co = cg * 64 + mt * 16 + (lane & 15);
  int k  = chk * 32 + 8 * (lane >> 4) + j;
  float v = w[((size_t)co * cin + k) * 9 + tap];
  f16 h = (f16)v;
  wh[idx] = h;
  wl[idx] = (f16)((v - (float)h) * 4096.0f);
}

// ---------------------------------------------------------------------------
// L1: direct f32 3->32 conv + BN + ReLU -> padded NHWC f32 [66][66][32]
// ---------------------------------------------------------------------------
__global__ __launch_bounds__(128) void conv_l1_kernel(
    const float* __restrict__ in,    // [nb][3][64][64]
    float* __restrict__ o32,         // [nb][66][66][32]
    const float* __restrict__ wt,    // [(c*9+tap)][32]
    const float* __restrict__ bconv,
    const float* __restrict__ gamma, const float* __restrict__ beta)
{
  __shared__ float sIn[3][18][20];
  __shared__ float sW[3][9][32];
  const int tile = blockIdx.x;
  const int b    = blockIdx.z;
  const int y0 = (tile >> 2) << 4, x0 = (tile & 3) << 4;
  const int tid = threadIdx.x;
  const int cg = tid >> 6;          // 0..1
  const int pg = tid & 63;
  const int py = pg >> 2, px0 = (pg & 3) << 2;

  float acc[4][16];
  #pragma unroll
  for (int i = 0; i < 4; ++i)
    #pragma unroll
    for (int j = 0; j < 16; ++j) acc[i][j] = 0.f;

  for (int idx = tid; idx < 3 * 324; idx += 128) {
    int c = idx / 324, rem = idx - c * 324;
    int iy = rem / 18, ix = rem - iy * 18;
    int gy = y0 - 1 + iy, gx = x0 - 1 + ix;
    float v = 0.f;
    if ((unsigned)gy < 64u && (unsigned)gx < 64u)
      v = in[(((size_t)b * 3 + c) << 12) + (gy << 6) + gx];
    sIn[c][iy][ix] = v;
  }
  for (int idx = tid; idx < 3 * 9 * 32; idx += 128) {
    int co = idx % 32;
    int rest = idx / 32;
    int tap = rest % 9, c = rest / 9;
    sW[c][tap][co] = wt[((size_t)c * 9 + tap) * 32 + co];
  }
  __syncthreads();
  for (int c = 0; c < 3; ++c) {
    #pragma unroll
    for (int dy = 0; dy < 3; ++dy) {
      const float* rowp = &sIn[c][py + dy][px0];
      float4 ra = *(const float4*)rowp;
      float4 rb = *(const float4*)(rowp + 4);
      float r[6] = {ra.x, ra.y, ra.z, ra.w, rb.x, rb.y};
      #pragma unroll
      for (int dx = 0; dx < 3; ++dx) {
        const float4* wp = (const float4*)&sW[c][dy * 3 + dx][cg * 16];
        float4 w0 = wp[0], w1 = wp[1], w2 = wp[2], w3 = wp[3];
        float wv[16] = {w0.x, w0.y, w0.z, w0.w, w1.x, w1.y, w1.z, w1.w,
                        w2.x, w2.y, w2.z, w2.w, w3.x, w3.y, w3.z, w3.w};
        #pragma unroll
        for (int i = 0; i < 4; ++i)
          #pragma unroll
          for (int j = 0; j < 16; ++j)
            acc[i][j] = fmaf(r[dx + i], wv[j], acc[i][j]);
      }
    }
  }
  #pragma unroll
  for (int j = 0; j < 16; ++j) {
    int co = cg * 16 + j;
    float sc = gamma[co] / sqrtf(1.0f + 1e-5f);
    float bb = bconv[co], sh = beta[co];
    #pragma unroll
    for (int i = 0; i < 4; ++i) {
      float v = (acc[i][j] + bb) * sc + sh;
      v = fmaxf(v, 0.f);
      o32[(((size_t)b * 66 + (y0 + py + 1)) * 66 + (x0 + px0 + i + 1)) * 32 + co] = v;
    }
  }
}

// ---------------------------------------------------------------------------
// MFMA implicit-GEMM 3x3 conv, f16x3 split (exact to ~2^-22 rel/product).
// (unchanged from round 6 -- proven)
// ---------------------------------------------------------------------------
template<int CIN, int COUT, bool F32OUT>
__global__ __launch_bounds__(512, 4) void mfmaconv_kernel(
    const float* __restrict__ x,
    float* __restrict__ onhwc,
    float* __restrict__ of32,
    const f16* __restrict__ wh, const f16* __restrict__ wl,
    const float* __restrict__ bconv,
    const float* __restrict__ gamma, const float* __restrict__ beta)
{
  constexpr int CHUNKS = CIN / 32;
  __shared__ __align__(16) char smem[396 * 32 * 2 * 2];   // 50688 B
  f16* sH = (f16*)smem;
  f16* sL = sH + 396 * 32;
  float (*sT)[33] = (float(*)[33])smem;                    // reused

  const int tid  = threadIdx.x;
  const int w    = tid >> 6, lane = tid & 63;
  const int l15  = lane & 15, lk = lane >> 4;
  const int rw   = w & 3, ch2 = w >> 2;
  const int tile = blockIdx.x;           // 0..15 (4 rows each)
  const int y0g  = tile << 2;
  const int cog  = blockIdx.y;
  const int cog0 = cog << 6;
  const int b    = blockIdx.z;

  f32x4 acc1[4][2], acc2[4][2];
  #pragma unroll
  for (int mt = 0; mt < 4; ++mt)
    #pragma unroll
    for (int n2 = 0; n2 < 2; ++n2) { acc1[mt][n2] = (f32x4)0.f; acc2[mt][n2] = (f32x4)0.f; }

  for (int chk = 0; chk < CHUNKS; ++chk) {
    __syncthreads();
    for (int idx = tid; idx < 3168; idx += 512) {
      int px = idx >> 3, c4 = idx & 7;
      int r = px / 66, c = px - r * 66;
      float4 v = *(const float4*)&x[(((size_t)b * 66 + y0g + r) * 66 + c) * CIN
                                    + chk * 32 + c4 * 4];
      float vv[4] = {v.x, v.y, v.z, v.w};
      f16x4 hv, lv;
      #pragma unroll
      for (int j = 0; j < 4; ++j) {
        f16 h = (f16)vv[j];
        hv[j] = h;
        lv[j] = (f16)((vv[j] - (float)h) * 4096.0f);
      }
      *(f16x4*)&sH[px * 32 + c4 * 4] = hv;
      *(f16x4*)&sL[px * 32 + c4 * 4] = lv;
    }
    __syncthreads();
    #pragma unroll
    for (int tap = 0; tap < 9; ++tap) {
      const int dy = tap / 3, dx = tap - dy * 3;
      f16x8 Bh[2], Bl[2];
      #pragma unroll
      for (int n2 = 0; n2 < 2; ++n2) {
        int hp = (rw + dy) * 66 + (ch2 * 32 + n2 * 16 + l15 + dx);
        Bh[n2] = *(const f16x8*)&sH[hp * 32 + 8 * lk];
        Bl[n2] = *(const f16x8*)&sL[hp * 32 + 8 * lk];
      }
      #pragma unroll
      for (int mt = 0; mt < 4; ++mt) {
        size_t aoff = ((((size_t)(cog * CHUNKS + chk) * 9 + tap) * 4 + mt) * 64 + lane) * 8;
        f16x8 Ah = *(const f16x8*)&wh[aoff];
        f16x8 Al = *(const f16x8*)&wl[aoff];
        #pragma unroll
        for (int n2 = 0; n2 < 2; ++n2) {
          acc1[mt][n2] = __builtin_amdgcn_mfma_f32_16x16x32_f16(Ah, Bh[n2], acc1[mt][n2], 0, 0, 0);
          acc2[mt][n2] = __builtin_amdgcn_mfma_f32_16x16x32_f16(Ah, Bl[n2], acc2[mt][n2], 0, 0, 0);
          acc2[mt][n2] = __builtin_amdgcn_mfma_f32_16x16x32_f16(Al, Bh[n2], acc2[mt][n2], 0, 0, 0);
        }
      }
    }
  }

  #pragma unroll
  for (int p = 0; p < 2; ++p) {
    __syncthreads();
    #pragma unroll
    for (int m1 = 0; m1 < 2; ++m1) {
      const int mt = 2 * p + m1;
      #pragma unroll
      for (int n2 = 0; n2 < 2; ++n2)
        #pragma unroll
        for (int i = 0; i < 4; ++i) {
          int co = cog0 + p * 32 + m1 * 16 + 4 * lk + i;
          float v = acc1[mt][n2][i] + acc2[mt][n2][i] * (1.0f / 4096.0f);
          float sc = gamma[co] / sqrtf(1.0f + 1e-5f);
          v = (v + bconv[co]) * sc + beta[co];
          v = fmaxf(v, 0.f);
          sT[rw * 64 + ch2 * 32 + n2 * 16 + l15][m1 * 16 + 4 * lk + i] = v;
        }
    }
    __syncthreads();
    if constexpr (F32OUT) {
      int co32 = tid >> 4, pxg = tid & 15;
      size_t base = (((size_t)b * COUT + cog0 + p * 32 + co32) << 12) + tile * 256 + pxg * 16;
      #pragma unroll
      for (int jj = 0; jj < 4; ++jj) {
        float4 o;
        o.x = sT[pxg * 16 + jj * 4 + 0][co32];
        o.y = sT[pxg * 16 + jj * 4 + 1][co32];
        o.z = sT[pxg * 16 + jj * 4 + 2][co32];
        o.w = sT[pxg * 16 + jj * 4 + 3][co32];
        *(float4*)&of32[base + jj * 4] = o;
      }
    } else {
      int px = tid >> 1, half = tid & 1;
      int row = px >> 6, col = px & 63;
      size_t base = (((size_t)b * 66 + y0g + row + 1) * 66 + col + 1) * COUT
                    + cog0 + p * 32 + half * 16;
      #pragma unroll
      for (int jj = 0; jj < 4; ++jj) {
        float4 o;
        o.x = sT[px][half * 16 + jj * 4 + 0];
        o.y = sT[px][half * 16 + jj * 4 + 1];
        o.z = sT[px][half * 16 + jj * 4 + 2];
        o.w = sT[px][half * 16 + jj * 4 + 3];
        *(float4*)&onhwc[base + jj * 4] = o;
      }
    }
  }
}

// ---------------------------------------------------------------------------
// last conv (256->1) + BN (no relu) + the three 1x1 heads fused. (unchanged)
// ---------------------------------------------------------------------------
__global__ __launch_bounds__(256) void conv_l4_heads_kernel(
    const float* __restrict__ in,       // [nb][256][64][64]
    const float* __restrict__ w4,       // [256*9]
    const float* __restrict__ b4, const float* __restrict__ gm4,
    const float* __restrict__ bt4,
    const float* __restrict__ cw, const float* __restrict__ cb,
    const float* __restrict__ gw, const float* __restrict__ gb,
    const float* __restrict__ ow, const float* __restrict__ ob,
    float* __restrict__ costout,
    float* __restrict__ geoout, float* __restrict__ obsout,
    int b0)
{
  __shared__ float sIn[8][18][20];
  __shared__ float sW[8][9];
  const int tile = blockIdx.x, b = blockIdx.y;
  const int y0 = (tile >> 2) << 4, x0 = (tile & 3) << 4;
  const int tid = threadIdx.x;
  const int py = tid >> 4, px = tid & 15;
  float acc = 0.f;
  for (int cc = 0; cc < 256; cc += 8) {
    __syncthreads();
    for (int idx = tid; idx < 8 * 324; idx += 256) {
      int c = idx / 324, rem = idx - c * 324;
      int iy = rem / 18, ix = rem - iy * 18;
      int gy = y0 - 1 + iy, gx = x0 - 1 + ix;
      float v = 0.f;
      if ((unsigned)gy < 64u && (unsigned)gx < 64u)
        v = in[(((size_t)b * 256 + cc + c) << 12) + (gy << 6) + gx];
      sIn[c][iy][ix] = v;
    }
    if (tid < 72) sW[tid / 9][tid % 9] = w4[(cc + tid / 9) * 9 + tid % 9];
    __syncthreads();
    #pragma unroll
    for (int c = 0; c < 8; ++c)
      #pragma unroll
      for (int dy = 0; dy < 3; ++dy)
        #pragma unroll
        for (int dx = 0; dx < 3; ++dx)
          acc = fmaf(sIn[c][py + dy][px + dx], sW[c][dy * 3 + dx], acc);
  }
  float sc = gm4[0] / sqrtf(1.0f + 1e-5f);
  float f  = (acc + b4[0]) * sc + bt4[0];
  float cv = 1.f / (1.f + expf(-(f * cw[0] + cb[0])));
  float gv = fmaxf(f * gw[0] + gb[0], 0.f);
  float ov = fmaxf(f * ow[0] + ob[0], 0.f);
  int gbi = b0 + b;
  int pix = ((y0 + py) << 6) + (x0 + px);
  costout[gbi * HW + pix] = cv;
  geoout[gbi * HW + pix]  = gv;
  obsout[gbi * HW + pix]  = ov;
}

// ---------------------------------------------------------------------------
// A* pass 1 -- single-wave per batch.  This round: (a) the two serial
// butterflies (argmax over row-registers + selected-row rescan) are merged
// into ONE 6-stage butterfly carrying two keys: kC = max(reg[masked], kB)
// for the global argmax, and kB (row-r snapshot+patches) whose result
// repairs lane r's register.  Coverage: rows != r via registers, row r via
// snapshot cells -- disjoint & exhaustive, so ordering/tie-breaks are exact.
// (b) no __syncthreads in the loop: 1 wave => LDS is in-order; removing it
// also removes the per-step vmcnt(0) drain of the global journal writes.
// (c) patch loop only over ballot set bits.
// ---------------------------------------------------------------------------
__global__ __launch_bounds__(64) void astar_pass1_kernel(
    const float* __restrict__ costm,
    const float* __restrict__ startm,
    const float* __restrict__ goalm,
    const float* __restrict__ mapd,
    unsigned short* __restrict__ Jmeta,
    unsigned short* __restrict__ Jcells)
{
  __shared__ float4 cell[HW];   // g, flag, hs(=heur+cost), cost
  __shared__ float2 pk[HW];     // fe, gc(=g+cost)
  const int b = blockIdx.x, lane = threadIdx.x;

  int gi = 0x7fffffff;
  for (int i = lane; i < HW; i += 64)
    if (goalm[b * HW + i] > 0.5f) gi = min(gi, i);
  #pragma unroll
  for (int m = 32; m; m >>= 1) gi = min(gi, __shfl_xor(gi, m));
  const int goal_idx = gi;
  const float gyf = (float)(goal_idx >> 6), gxf = (float)(goal_idx & 63);

  for (int i = lane; i < HW; i += 64) {
    float c_ = costm[b * HW + i];
    float iy = (float)(i >> 6), ix = (float)(i & 63);
    float d0 = fabsf(iy - gyf), d1 = fabsf(ix - gxf);
    float cheb = (d0 + d1) - fminf(d0, d1);
    float euc  = sqrtf(d0 * d0 + d1 * d1);
    float h = (cheb + 0.001f * euc) + c_;
    bool st = startm[b * HW + i] > 0.5f;
    float flg = st ? 1.f : ((mapd[b * HW + i] > 0.5f) ? 0.f : 2.f);
    cell[i] = make_float4(0.f, flg, h, c_);
    pk[i] = make_float2(st ? expf(-((0.5f * h) * 0.125f)) : 0.f, c_);
  }
  __syncthreads();

  // per-lane row registers: (max fe, first idx, gc) of row `lane`
  float gm = -1.f; int gidx = 0; float ggc = 0.f;
  {
    int base = lane << 6;
    for (int k = 0; k < 64; ++k) {
      int ci = base + ((k + lane) & 63);
      float2 p = pk[ci];
      if (p.x > gm || (p.x == gm && ci < gidx)) { gm = p.x; gidx = ci; ggc = p.y; }
    }
  }

  // bootstrap argmax (plain butterfly over registers)
  float v = gm; int idx = gidx; float gc = ggc;
  #pragma unroll
  for (int m = 32; m; m >>= 1) {
    float vo = __shfl_xor(v, m);
    int   io = __shfl_xor(idx, m);
    float co = __shfl_xor(gc, m);
    bool take = (vo > v) || (vo == v && io < idx);
    if (take) { v = vo; idx = io; gc = co; }
  }

  int t = 0;
  for (; t < 512; ++t) {
    const int ind = idx;
    const float g2 = gc;
    const bool unsolved = (ind != goal_idx);
    const int r = ind >> 6, cx = ind & 63;

    // snapshot read of row r, issued before any update writes (in-order LDS)
    const int rb = (r << 6) + lane;
    float2 rp = pk[rb];

    int pcell = -1; float pval = 0.f, pgc = 0.f;
    if (lane < 8) {
      int kk = (lane >= 4) ? lane + 1 : lane;
      int ny = r + (kk / 3) - 1, nx = cx + (kk % 3) - 1;
      if ((unsigned)ny < 64u && (unsigned)nx < 64u) {
        int n = (ny << 6) + nx;
        float4 cd = cell[n];
        bool trig = (cd.y == 1.f) ? (cd.x > g2) : (cd.y == 0.f);
        if (trig) {
          float fv = expf(-((0.5f * g2 + 0.5f * cd.z) * 0.125f));
          *(float2*)&cell[n] = make_float2(g2, 1.f);
          pk[n] = make_float2(fv, g2 + cd.w);
          pcell = n; pval = fv; pgc = g2 + cd.w;
        }
      }
      Jcells[((size_t)b * 512 + t) * 8 + lane] =
          (unsigned short)(pcell >= 0 ? pcell : 0xFFFF);
    } else if (lane == 8) {
      if (unsolved) {
        cell[ind].y = 2.f;
        pk[ind].x  = 0.f;
      }
      Jmeta[b * 512 + t] = (unsigned short)(ind | (unsolved ? 0 : 0x8000));
    }

    // kB: row-r candidate (snapshot + removal + patches)
    float bv = (unsolved && lane == cx) ? -1.f : rp.x;
    int bi = rb; float bgc = rp.y;

    unsigned long long pm = __ballot(pcell >= 0);
    const bool fixpoint = (!unsolved) && (pm == 0ull);
    if (fixpoint) { ++t; break; }

    while (pm) {
      int k = (int)__ffsll(pm) - 1; pm &= pm - 1;
      int   pc = __shfl(pcell, k);
      float pv = __shfl(pval, k);
      float pg = __shfl(pgc, k);
      if ((pc >> 6) == r && (pc & 63) == lane) {
        if (pv > bv || (pv == bv && pc < bi)) { bv = pv; bi = pc; bgc = pg; }
      }
      if ((pc >> 6) == lane) {
        if (pv > gm || (pv == gm && pc < gidx)) { gm = pv; gidx = pc; ggc = pg; }
      }
    }

    // combined key kC = max(reg masked at lane r, kB)
    float cv; int ci; float cgc;
    if (unsolved && lane == r) { cv = bv; ci = bi; cgc = bgc; }
    else if (gm > bv || (gm == bv && gidx < bi)) { cv = gm; ci = gidx; cgc = ggc; }
    else { cv = bv; ci = bi; cgc = bgc; }

    // single 6-stage butterfly carrying (kC) and (kB)
    #pragma unroll
    for (int m = 32; m; m >>= 1) {
      float vo  = __shfl_xor(cv, m);
      int   io  = __shfl_xor(ci, m);
      float co  = __shfl_xor(cgc, m);
      float bvo = __shfl_xor(bv, m);
      int   bio = __shfl_xor(bi, m);
      float bgo = __shfl_xor(bgc, m);
      if (vo > cv || (vo == cv && io < ci)) { cv = vo; ci = io; cgc = co; }
      if (bvo > bv || (bvo == bv && bio < bi)) { bv = bvo; bi = bio; bgc = bgo; }
    }
    if (unsolved && lane == r) { gm = bv; gidx = bi; ggc = bgc; }
    v = cv; idx = ci; gc = cgc;
    // no barrier: single wave, LDS in-order; journal writes drain async
  }

  {
    unsigned short jm = (unsigned short)(goal_idx | 0x8000);
    uint4* jc4 = (uint4*)Jcells;
    for (int tt = t + lane; tt < 512; tt += 64) {
      Jmeta[b * 512 + tt] = jm;
      jc4[(size_t)b * 512 + tt] =
          make_uint4(0xFFFFFFFFu, 0xFFFFFFFFu, 0xFFFFFFFFu, 0xFFFFFFFFu);
    }
  }
}

// ---------------------------------------------------------------------------
// A* pass 2 (unchanged)
// ---------------------------------------------------------------------------
__global__ __launch_bounds__(64) void astar_pass2_kernel(
    const unsigned short* __restrict__ Jmeta,
    const unsigned short* __restrict__ Jcells,
    const float* __restrict__ goalm,
    float* __restrict__ out_hist, float* __restrict__ out_path)
{
  __shared__ unsigned short par[HW];
  __shared__ unsigned short jm[64];
  __shared__ unsigned short jc[64][8];
  const int b = blockIdx.x, lane = threadIdx.x;

  for (int i = lane; i < HW; i += 64) {
    out_hist[b * HW + i] = 0.f;
    out_path[b * HW + i] = 0.f;
  }
  int localmin = 512;
  for (int t = lane; t < 512; t += 64) {
    bool all16 = true;
    for (int bb = 0; bb < 16; ++bb)
      all16 = all16 && ((Jmeta[bb * 512 + t] & 0x8000u) != 0);
    if (all16) localmin = min(localmin, t);
  }
  #pragma unroll
  for (int m = 32; m; m >>= 1) localmin = min(localmin, __shfl_xor(localmin, m));
  const int t_last = (localmin < 512) ? localmin : 511;

  int gi = 0x7fffffff;
  for (int i = lane; i < HW; i += 64)
    if (goalm[b * HW + i] > 0.5f) gi = min(gi, i);
  #pragma unroll
  for (int m = 32; m; m >>= 1) gi = min(gi, __shfl_xor(gi, m));

  for (int i = lane; i < HW; i += 64) par[i] = (unsigned short)gi;
  __syncthreads();

  for (int t0 = 0; t0 <= t_last; t0 += 64) {
    if (t0 + lane < 512) {
      jm[lane] = Jmeta[b * 512 + t0 + lane];
      const unsigned short* src = &Jcells[((size_t)b * 512 + t0 + lane) * 8];
      #pragma unroll
      for (int k = 0; k < 8; ++k) jc[lane][k] = src[k];
    }
    __syncthreads();
    int te = min(t_last - t0, 63);
    for (int tt = 0; tt <= te; ++tt) {
      int ind = jm[tt] & 0x0FFF;
      if (lane < 8) {
        unsigned short c = jc[tt][lane];
        if (c != 0xFFFFu) par[c] = (unsigned short)ind;
      } else if (lane == 8) {
        out_hist[b * HW + ind] = 1.0f;
      }
    }
    __syncthreads();
  }
  if (lane == 0) {
    out_path[b * HW + gi] = 1.0f;
    int loc = par[gi];
    for (int i = 0; i < t_last; ++i) {
      out_path[b * HW + loc] = 1.0f;
      loc = par[loc];
    }
  }
}

// ---------------------------------------------------------------------------
extern "C" void kernel_launch(void* const* d_in, const int* in_sizes, int n_in,
                              void* d_out, int out_size, void* d_ws, size_t ws_size,
                              hipStream_t stream)
{
  (void)in_sizes; (void)n_in; (void)out_size;
  const float* mapd   = (const float*)d_in[0];
  const float* startm = (const float*)d_in[1];
  const float* goalm  = (const float*)d_in[2];
  const float* w0 = (const float*)d_in[3];
  const float* b0 = (const float*)d_in[4];
  const float* gm0= (const float*)d_in[5];
  const float* bt0= (const float*)d_in[6];
  const float* w1 = (const float*)d_in[7];
  const float* b1 = (const float*)d_in[8];
  const float* gm1= (const float*)d_in[9];
  const float* bt1= (const float*)d_in[10];
  const float* w2 = (const float*)d_in[11];
  const float* b2 = (const float*)d_in[12];
  const float* gm2= (const float*)d_in[13];
  const float* bt2= (const float*)d_in[14];
  const float* w3 = (const float*)d_in[15];
  const float* b3 = (const float*)d_in[16];
  const float* gm3= (const float*)d_in[17];
  const float* bt3= (const float*)d_in[18];
  const float* w4 = (const float*)d_in[19];
  const float* b4 = (const float*)d_in[20];
  const float* gm4= (const float*)d_in[21];
  const float* bt4= (const float*)d_in[22];
  const float* cw = (const float*)d_in[23];
  const float* cb = (const float*)d_in[24];
  const float* gw = (const float*)d_in[25];
  const float* gb = (const float*)d_in[26];
  const float* owp= (const float*)d_in[27];
  const float* obp= (const float*)d_in[28];
  float* out = (float*)d_out;

  char* wsb = (char*)d_ws;
  size_t off = 0;
  auto alloc = [&](size_t bytes) {
    void* p = wsb + off;
    off = (off + bytes + 255) & ~(size_t)255;
    return p;
  };
  float* wt0 = (float*)alloc(3 * 9 * 32 * 4);
  f16* wh1 = (f16*)alloc(64  * 9 * 32  * 2);
  f16* wl1 = (f16*)alloc(64  * 9 * 32  * 2);
  f16* wh2 = (f16*)alloc(128 * 9 * 64  * 2);
  f16* wl2 = (f16*)alloc(128 * 9 * 64  * 2);
  f16* wh3 = (f16*)alloc(256 * 9 * 128 * 2);
  f16* wl3 = (f16*)alloc(256 * 9 * 128 * 2);
  float* in3   = (float*)alloc(16 * 3 * HW * 4);
  float* costb = (float*)alloc(16 * HW * 4);
  unsigned short* Jmeta  = (unsigned short*)alloc(16 * 512 * 2);
  unsigned short* Jcells = (unsigned short*)alloc(16 * 512 * 8 * 2);
  size_t fixed = off;

  const size_t A32  = 66 * 66 * 32  * 4;
  const size_t B64  = 66 * 66 * 64  * 4;
  const size_t A128 = 66 * 66 * 128 * 4;
  const size_t L4O  = 256 * HW * 4;
  const size_t perG = A32 + B64 + A128 + L4O + 4 * 256;

  int G = 16;
  while (G > 1 && fixed + (size_t)G * perG > ws_size) G >>= 1;

  float* a32f  = (float*)alloc(G * A32);
  float* b64f  = (float*)alloc(G * B64);
  float* a128f = (float*)alloc(G * A128);
  float* l4o   = (float*)alloc(G * L4O);

  pack3_kernel<<<(16 * 3 * HW + 255) / 256, 256, 0, stream>>>(mapd, startm, goalm, in3);
  wtrans_kernel<<<(3 * 9 * 32 + 255) / 256, 256, 0, stream>>>(w0, wt0, 3, 32);
  wrepack_kernel<<<(64 * 9 * 32 + 255) / 256, 256, 0, stream>>>(w1, wh1, wl1, 32, 64);
  wrepack_kernel<<<(128 * 9 * 64 + 255) / 256, 256, 0, stream>>>(w2, wh2, wl2, 64, 128);
  wrepack_kernel<<<(256 * 9 * 128 + 255) / 256, 256, 0, stream>>>(w3, wh3, wl3, 128, 256);

  hipMemsetAsync(a32f,  0, G * A32,  stream);
  hipMemsetAsync(b64f,  0, G * B64,  stream);
  hipMemsetAsync(a128f, 0, G * A128, stream);

  for (int g0 = 0; g0 < 16; g0 += G) {
    conv_l1_kernel<<<dim3(16, 1, G), 128, 0, stream>>>(
        in3 + (size_t)g0 * 3 * HW, a32f, wt0, b0, gm0, bt0);
    mfmaconv_kernel<32, 64, false><<<dim3(16, 1, G), 512, 0, stream>>>(
        a32f, b64f, nullptr, wh1, wl1, b1, gm1, bt1);
    mfmaconv_kernel<64, 128, false><<<dim3(16, 2, G), 512, 0, stream>>>(
        b64f, a128f, nullptr, wh2, wl2, b2, gm2, bt2);
    mfmaconv_kernel<128, 256, true><<<dim3(16, 4, G), 512, 0, stream>>>(
        a128f, nullptr, l4o, wh3, wl3, b3, gm3, bt3);
    conv_l4_heads_kernel<<<dim3(16, G), 256, 0, stream>>>(
        l4o, w4, b4, gm4, bt4, cw, cb, gw, gb, owp, obp,
        costb, out + 2 * 16 * HW, out + 3 * 16 * HW, g0);
  }

  astar_pass1_kernel<<<16, 64, 0, stream>>>(costb, startm, goalm, mapd, Jmeta, Jcells);
  astar_pass2_kernel<<<16, 64, 0, stream>>>(Jmeta, Jcells, goalm, out, out + 16 * HW);
}